// Round 1
// baseline (279.846 us; speedup 1.0000x reference)
//
#include <hip/hip_runtime.h>

#define L2E 1.44269504088896f

typedef unsigned short u16;
typedef __attribute__((ext_vector_type(8))) short bf16x8;
typedef __attribute__((ext_vector_type(4))) float f32x4;
typedef __attribute__((ext_vector_type(4))) unsigned int u32x4;

__device__ __forceinline__ u16 f2bf(float x) {
  union { float f; unsigned u; } a; a.f = x;
  return (u16)((a.u + 0x7fffu + ((a.u >> 16) & 1u)) >> 16);
}

// ---------------- fp32 -> bf16 elementwise (x4 vectorized) ----------------
__global__ __launch_bounds__(256) void cvt_bf16(const float* __restrict__ in,
                                                u16* __restrict__ out, int n4) {
  int i = blockIdx.x * 256 + threadIdx.x;
  int stride = gridDim.x * 256;
  for (; i < n4; i += stride) {
    float4 v = reinterpret_cast<const float4*>(in)[i];
    ushort4 o;
    o.x = f2bf(v.x); o.y = f2bf(v.y); o.z = f2bf(v.z); o.w = f2bf(v.w);
    reinterpret_cast<ushort4*>(out)[i] = o;
  }
}

// ---------------- fp32 [K][N] -> bf16 [N][K] (tiled transpose) ----------------
__global__ __launch_bounds__(256) void transpose_cvt(const float* __restrict__ in,
                                                     u16* __restrict__ out,
                                                     int K, int N) {
  __shared__ float tile[32][33];
  int n0 = blockIdx.x * 32, k0 = blockIdx.y * 32;
  int tx = threadIdx.x & 31, ty = threadIdx.x >> 5;  // ty in [0,8)
  for (int r = ty; r < 32; r += 8)
    tile[r][tx] = in[(k0 + r) * N + n0 + tx];
  __syncthreads();
  for (int r = ty; r < 32; r += 8)
    out[(n0 + r) * K + k0 + tx] = f2bf(tile[tx][r]);
}

// ---------------- QKV GEMM: [4096,1024]bf16 @ [1024,3072] (+bias) ----------------
// A row-major [4096][1024]; Bt row-major [3072][1024] (pre-transposed weights).
// Epilogue scatters to Q[b][h][s][d], K[b][h][s][d], Vt[b][h][d][s] (bf16).
__global__ __launch_bounds__(256) void gemm_qkv(
    const u16* __restrict__ A, const u16* __restrict__ Bt,
    const float* __restrict__ bias,
    u16* __restrict__ Qo, u16* __restrict__ Ko, u16* __restrict__ Vt) {
  __shared__ __attribute__((aligned(16))) u16 As[128 * 32];
  __shared__ __attribute__((aligned(16))) u16 Bs[128 * 32];
  const int t = threadIdx.x;
  const int m0 = blockIdx.y * 128;
  const int n0 = blockIdx.x * 128;
  const int w = t >> 6, l = t & 63;
  const int wr = (w >> 1) * 64, wc = (w & 1) * 64;
  const int lr = l & 15, lk = l >> 4;
  f32x4 acc[4][4] = {};

  for (int kt = 0; kt < 32; ++kt) {
    const int k0 = kt * 32;
    // stage A and B tiles: 128 rows x 4 chunks(16B) each, XOR-swizzled
    for (int i = 0; i < 2; ++i) {
      int id = t + 256 * i;
      int row = id >> 2, ch = id & 3;
      int sw = ch ^ ((row >> 1) & 3);
      *reinterpret_cast<u32x4*>(&As[row * 32 + sw * 8]) =
          *reinterpret_cast<const u32x4*>(&A[(m0 + row) * 1024 + k0 + ch * 8]);
      *reinterpret_cast<u32x4*>(&Bs[row * 32 + sw * 8]) =
          *reinterpret_cast<const u32x4*>(&Bt[(n0 + row) * 1024 + k0 + ch * 8]);
    }
    __syncthreads();
    bf16x8 a[4], b[4];
    for (int mf = 0; mf < 4; ++mf) {
      int row = wr + mf * 16 + lr;
      int sw = lk ^ ((row >> 1) & 3);
      a[mf] = *reinterpret_cast<const bf16x8*>(&As[row * 32 + sw * 8]);
    }
    for (int nf = 0; nf < 4; ++nf) {
      int row = wc + nf * 16 + lr;
      int sw = lk ^ ((row >> 1) & 3);
      b[nf] = *reinterpret_cast<const bf16x8*>(&Bs[row * 32 + sw * 8]);
    }
    for (int mf = 0; mf < 4; ++mf)
      for (int nf = 0; nf < 4; ++nf)
        acc[mf][nf] = __builtin_amdgcn_mfma_f32_16x16x32_bf16(a[mf], b[nf],
                                                              acc[mf][nf], 0, 0, 0);
    __syncthreads();
  }
  // epilogue: C row = (l>>4)*4 + r, col = l&15 per 16x16 frag
  for (int mf = 0; mf < 4; ++mf)
    for (int nf = 0; nf < 4; ++nf)
      for (int r = 0; r < 4; ++r) {
        int gr = m0 + wr + mf * 16 + lk * 4 + r;
        int gc = n0 + wc + nf * 16 + lr;
        float v = acc[mf][nf][r] + bias[gc];
        int b_ = gr >> 11, s = gr & 2047;
        int h = gc / 192, j = gc - h * 192;
        int part = j >> 6, d = j & 63;
        u16 bv = f2bf(v);
        if (part == 0)
          Qo[((b_ * 16 + h) * 2048 + s) * 64 + d] = bv;
        else if (part == 1)
          Ko[((b_ * 16 + h) * 2048 + s) * 64 + d] = bv;
        else
          Vt[((b_ * 16 + h) * 64 + d) * 2048 + s] = bv;
      }
}

// ---------------- flash attention: 1 block per (b,h,q-tile of 64) ----------------
__global__ __launch_bounds__(256) void attn(
    const u16* __restrict__ Q, const u16* __restrict__ K,
    const u16* __restrict__ Vt, u16* __restrict__ ctx) {
  __shared__ __attribute__((aligned(16))) u16 Ks[64 * 64];
  __shared__ __attribute__((aligned(16))) u16 Vs[64 * 64];
  __shared__ __attribute__((aligned(16))) u16 Ps[4][16 * 64];
  const int t = threadIdx.x;
  const int w = t >> 6, l = t & 63;
  const int bh = blockIdx.x >> 5;  // [0,32)
  const int qt = blockIdx.x & 31;
  const int b = bh >> 4, h = bh & 15;
  const int q0 = qt * 64;
  const u16* Qp = Q + bh * (2048 * 64);
  const u16* Kp = K + bh * (2048 * 64);
  const u16* Vp = Vt + bh * (64 * 2048);
  const int lr = l & 15, lk = l >> 4;
  const float SC = 0.125f * L2E;  // score scale folded into exp2 domain

  // Q fragments for this wave's 16 rows, held in registers
  bf16x8 qf[2];
  for (int kk = 0; kk < 2; ++kk)
    qf[kk] = *reinterpret_cast<const bf16x8*>(
        &Qp[(q0 + w * 16 + lr) * 64 + kk * 32 + lk * 8]);

  f32x4 o[4] = {};
  float mrun[4], lrun[4];
  for (int r = 0; r < 4; ++r) { mrun[r] = -1e30f; lrun[r] = 0.f; }

  for (int kt = 0; kt < 32; ++kt) {
    const int k0 = kt * 64;
    // stage K (row-major [krow][d]) and Vt ([d][krow]) tiles, XOR-swizzled
    for (int i = 0; i < 2; ++i) {
      int id = t + 256 * i;
      int row = id >> 3, ch = id & 7;
      int sw = ch ^ (row & 7);
      *reinterpret_cast<u32x4*>(&Ks[row * 64 + sw * 8]) =
          *reinterpret_cast<const u32x4*>(&Kp[(k0 + row) * 64 + ch * 8]);
      *reinterpret_cast<u32x4*>(&Vs[row * 64 + sw * 8]) =
          *reinterpret_cast<const u32x4*>(&Vp[row * 2048 + k0 + ch * 8]);
    }
    __syncthreads();

    // S = Q K^T for 16 q-rows x 64 k-cols
    f32x4 s[4] = {};
    for (int nb = 0; nb < 4; ++nb) {
      int row = nb * 16 + lr;
      for (int kk = 0; kk < 2; ++kk) {
        int ch = kk * 4 + lk;
        int sw = ch ^ (row & 7);
        bf16x8 kf = *reinterpret_cast<const bf16x8*>(&Ks[row * 64 + sw * 8]);
        s[nb] = __builtin_amdgcn_mfma_f32_16x16x32_bf16(qf[kk], kf, s[nb], 0, 0, 0);
      }
    }
    // scale into exp2 domain
    for (int nb = 0; nb < 4; ++nb)
      for (int r = 0; r < 4; ++r) s[nb][r] *= SC;

    // row max across 4 col-frags + 16-lane group
    float tm[4];
    for (int r = 0; r < 4; ++r)
      tm[r] = fmaxf(fmaxf(s[0][r], s[1][r]), fmaxf(s[2][r], s[3][r]));
    for (int mask = 1; mask < 16; mask <<= 1)
      for (int r = 0; r < 4; ++r)
        tm[r] = fmaxf(tm[r], __shfl_xor(tm[r], mask));

    float al[4], mnew[4];
    for (int r = 0; r < 4; ++r) {
      mnew[r] = fmaxf(mrun[r], tm[r]);
      al[r] = exp2f(mrun[r] - mnew[r]);
      mrun[r] = mnew[r];
    }
    f32x4 ps[4];
    for (int nb = 0; nb < 4; ++nb)
      for (int r = 0; r < 4; ++r)
        ps[nb][r] = exp2f(s[nb][r] - mnew[r]);
    float rs[4];
    for (int r = 0; r < 4; ++r)
      rs[r] = ps[0][r] + ps[1][r] + ps[2][r] + ps[3][r];
    for (int mask = 1; mask < 16; mask <<= 1)
      for (int r = 0; r < 4; ++r) rs[r] += __shfl_xor(rs[r], mask);
    for (int r = 0; r < 4; ++r) lrun[r] = lrun[r] * al[r] + rs[r];
    for (int nb = 0; nb < 4; ++nb)
      for (int r = 0; r < 4; ++r) o[nb][r] *= al[r];

    // bounce P through wave-private LDS to A-fragment layout
    u16* Pw = Ps[w];
    for (int nb = 0; nb < 4; ++nb)
      for (int r = 0; r < 4; ++r) {
        int row = lk * 4 + r;
        int col = nb * 16 + lr;
        int sw = (col >> 3) ^ (row & 7);
        Pw[row * 64 + sw * 8 + (col & 7)] = f2bf(ps[nb][r]);
      }
    bf16x8 pf[2];
    for (int kk = 0; kk < 2; ++kk) {
      int ch = kk * 4 + lk;
      int sw = ch ^ (lr & 7);
      pf[kk] = *reinterpret_cast<const bf16x8*>(&Pw[lr * 64 + sw * 8]);
    }
    // O += P V  (B operand from Vt tile: contiguous krow)
    for (int nb = 0; nb < 4; ++nb) {
      int row = nb * 16 + lr;
      for (int kk = 0; kk < 2; ++kk) {
        int ch = kk * 4 + lk;
        int sw = ch ^ (row & 7);
        bf16x8 vf = *reinterpret_cast<const bf16x8*>(&Vs[row * 64 + sw * 8]);
        o[nb] = __builtin_amdgcn_mfma_f32_16x16x32_bf16(pf[kk], vf, o[nb], 0, 0, 0);
      }
    }
    __syncthreads();
  }
  // epilogue: normalize and store ctx[b][s][h*64+d] bf16
  for (int r = 0; r < 4; ++r) lrun[r] = 1.0f / lrun[r];
  for (int nb = 0; nb < 4; ++nb)
    for (int r = 0; r < 4; ++r) {
      int s_ = q0 + w * 16 + lk * 4 + r;
      int d = nb * 16 + lr;
      ctx[(b * 2048 + s_) * 1024 + h * 64 + d] = f2bf(o[nb][r] * lrun[r]);
    }
}

// ---------------- dense GEMM: ctx[4096,1024]bf16 @ [1024,1024] (+bias) -> fp32 ----------------
__global__ __launch_bounds__(256) void gemm_dense(
    const u16* __restrict__ A, const u16* __restrict__ Bt,
    const float* __restrict__ bias, float* __restrict__ out) {
  __shared__ __attribute__((aligned(16))) u16 As[128 * 32];
  __shared__ __attribute__((aligned(16))) u16 Bs[128 * 32];
  const int t = threadIdx.x;
  const int m0 = blockIdx.y * 128;
  const int n0 = blockIdx.x * 128;
  const int w = t >> 6, l = t & 63;
  const int wr = (w >> 1) * 64, wc = (w & 1) * 64;
  const int lr = l & 15, lk = l >> 4;
  f32x4 acc[4][4] = {};

  for (int kt = 0; kt < 32; ++kt) {
    const int k0 = kt * 32;
    for (int i = 0; i < 2; ++i) {
      int id = t + 256 * i;
      int row = id >> 2, ch = id & 3;
      int sw = ch ^ ((row >> 1) & 3);
      *reinterpret_cast<u32x4*>(&As[row * 32 + sw * 8]) =
          *reinterpret_cast<const u32x4*>(&A[(m0 + row) * 1024 + k0 + ch * 8]);
      *reinterpret_cast<u32x4*>(&Bs[row * 32 + sw * 8]) =
          *reinterpret_cast<const u32x4*>(&Bt[(n0 + row) * 1024 + k0 + ch * 8]);
    }
    __syncthreads();
    bf16x8 a[4], b[4];
    for (int mf = 0; mf < 4; ++mf) {
      int row = wr + mf * 16 + lr;
      int sw = lk ^ ((row >> 1) & 3);
      a[mf] = *reinterpret_cast<const bf16x8*>(&As[row * 32 + sw * 8]);
    }
    for (int nf = 0; nf < 4; ++nf) {
      int row = wc + nf * 16 + lr;
      int sw = lk ^ ((row >> 1) & 3);
      b[nf] = *reinterpret_cast<const bf16x8*>(&Bs[row * 32 + sw * 8]);
    }
    for (int mf = 0; mf < 4; ++mf)
      for (int nf = 0; nf < 4; ++nf)
        acc[mf][nf] = __builtin_amdgcn_mfma_f32_16x16x32_bf16(a[mf], b[nf],
                                                              acc[mf][nf], 0, 0, 0);
    __syncthreads();
  }
  for (int mf = 0; mf < 4; ++mf)
    for (int nf = 0; nf < 4; ++nf)
      for (int r = 0; r < 4; ++r) {
        int gr = m0 + wr + mf * 16 + lk * 4 + r;
        int gc = n0 + wc + nf * 16 + lr;
        out[gr * 1024 + gc] = acc[mf][nf][r] + bias[gc];
      }
}

extern "C" void kernel_launch(void* const* d_in, const int* in_sizes, int n_in,
                              void* d_out, int out_size, void* d_ws, size_t ws_size,
                              hipStream_t stream) {
  const float* hs = (const float*)d_in[0];       // [2,2048,1024]
  const float* w_qkv = (const float*)d_in[1];    // [1024,3072]
  const float* b_qkv = (const float*)d_in[2];    // [3072]
  const float* w_dense = (const float*)d_in[3];  // [1024,1024]
  const float* b_dense = (const float*)d_in[4];  // [1024]
  float* out = (float*)d_out;

  char* ws = (char*)d_ws;
  u16* hsb = (u16*)(ws);                       // 8 MB  [4096][1024]
  u16* wqkvT = (u16*)(ws + (8ll << 20));       // 6 MB  [3072][1024]
  u16* wdT = (u16*)(ws + (14ll << 20));        // 2 MB  [1024][1024]
  u16* Qb = (u16*)(ws + (16ll << 20));         // 8 MB  [2][16][2048][64]
  u16* Kb = (u16*)(ws + (24ll << 20));         // 8 MB
  u16* Vtb = (u16*)(ws + (32ll << 20));        // 8 MB  [2][16][64][2048]
  u16* ctx = (u16*)(ws + (40ll << 20));        // 8 MB  [4096][1024]

  cvt_bf16<<<dim3(2048), dim3(256), 0, stream>>>(hs, hsb, (4096 * 1024) / 4);
  transpose_cvt<<<dim3(96, 32), dim3(256), 0, stream>>>(w_qkv, wqkvT, 1024, 3072);
  transpose_cvt<<<dim3(32, 32), dim3(256), 0, stream>>>(w_dense, wdT, 1024, 1024);
  gemm_qkv<<<dim3(24, 32), dim3(256), 0, stream>>>(hsb, wqkvT, b_qkv, Qb, Kb, Vtb);
  attn<<<dim3(1024), dim3(256), 0, stream>>>(Qb, Kb, Vtb, ctx);
  gemm_dense<<<dim3(8, 32), dim3(256), 0, stream>>>(ctx, wdT, b_dense, out);
}

// Round 4
// 217.303 us; speedup vs baseline: 1.2878x; 1.2878x over previous
//
#include <hip/hip_runtime.h>

#define L2E 1.44269504088896f

typedef unsigned short u16;
typedef __attribute__((ext_vector_type(8))) short bf16x8;
typedef __attribute__((ext_vector_type(4))) float f32x4;
typedef __attribute__((ext_vector_type(16))) float f32x16;

__device__ __forceinline__ u16 f2bf(float x) {
  union { float f; unsigned u; } a; a.f = x;
  return (u16)((a.u + 0x7fffu + ((a.u >> 16) & 1u)) >> 16);
}

__device__ __forceinline__ unsigned cvtpk(float lo, float hi) {
  unsigned r;
  asm("v_cvt_pk_bf16_f32 %0, %1, %2" : "=v"(r) : "v"(lo), "v"(hi));
  return r;
}

__device__ __forceinline__ float fexp2(float x) {
  float r;
  asm("v_exp_f32 %0, %1" : "=v"(r) : "v"(x));
  return r;
}

__device__ __forceinline__ void gll16(const u16* g, u16* lds) {
  __builtin_amdgcn_global_load_lds(
      (const __attribute__((address_space(1))) unsigned int*)g,
      (__attribute__((address_space(3))) unsigned int*)lds, 16, 0, 0);
}

// ---------------- fp32 -> bf16 elementwise (x4 vectorized) ----------------
__global__ __launch_bounds__(256) void cvt_bf16(const float* __restrict__ in,
                                                u16* __restrict__ out, int n4) {
  int i = blockIdx.x * 256 + threadIdx.x;
  int stride = gridDim.x * 256;
  for (; i < n4; i += stride) {
    float4 v = reinterpret_cast<const float4*>(in)[i];
    ushort4 o;
    o.x = f2bf(v.x); o.y = f2bf(v.y); o.z = f2bf(v.z); o.w = f2bf(v.w);
    reinterpret_cast<ushort4*>(out)[i] = o;
  }
}

// ---------------- fp32 [K][N] -> bf16 [N][K] (tiled transpose) ----------------
__global__ __launch_bounds__(256) void transpose_cvt(const float* __restrict__ in,
                                                     u16* __restrict__ out,
                                                     int K, int N) {
  __shared__ float tile[32][33];
  int n0 = blockIdx.x * 32, k0 = blockIdx.y * 32;
  int tx = threadIdx.x & 31, ty = threadIdx.x >> 5;
  for (int r = ty; r < 32; r += 8)
    tile[r][tx] = in[(k0 + r) * N + n0 + tx];
  __syncthreads();
  for (int r = ty; r < 32; r += 8)
    out[(n0 + r) * K + k0 + tx] = f2bf(tile[tx][r]);
}

// ---------------- QKV GEMM (m97 structure): [4096,1024]bf16 @ Bt[3072,1024] ----------------
__global__ __launch_bounds__(256) void gemm_qkv(
    const u16* __restrict__ A, const u16* __restrict__ Bt,
    const float* __restrict__ bias,
    u16* __restrict__ Qo, u16* __restrict__ Ko, u16* __restrict__ Vt) {
  __shared__ __attribute__((aligned(16))) u16 As[128 * 64];
  __shared__ __attribute__((aligned(16))) u16 Bs[128 * 64];
  const int t = threadIdx.x, w = t >> 6, l = t & 63;
  const int m0 = blockIdx.y * 128, n0 = blockIdx.x * 128;
  const int lr = l & 15, lk = l >> 4;
  const int wr = (w >> 1) * 64, wc = (w & 1) * 64;
  const int sr = l >> 3;                 // 0..7
  const int sch = (l & 7) ^ sr;          // swizzled chunk for staging source
  f32x4 acc[4][4] = {};

  for (int kt = 0; kt < 16; ++kt) {
    const int k0 = kt * 64;
    __syncthreads();
#pragma unroll
    for (int j = 0; j < 4; ++j) {
      const int row = w * 32 + j * 8 + sr;
      gll16(A + (size_t)(m0 + row) * 1024 + k0 + sch * 8, &As[(w * 32 + j * 8) * 64]);
      gll16(Bt + (size_t)(n0 + row) * 1024 + k0 + sch * 8, &Bs[(w * 32 + j * 8) * 64]);
    }
    asm volatile("s_waitcnt vmcnt(0)");
    __syncthreads();
#pragma unroll
    for (int kk = 0; kk < 2; ++kk) {
      bf16x8 a[4], b[4];
#pragma unroll
      for (int mf = 0; mf < 4; ++mf) {
        const int row = wr + mf * 16 + lr;
        const int ch = (kk * 4 + lk) ^ (row & 7);
        a[mf] = *reinterpret_cast<const bf16x8*>(&As[row * 64 + ch * 8]);
      }
#pragma unroll
      for (int nf = 0; nf < 4; ++nf) {
        const int row = wc + nf * 16 + lr;
        const int ch = (kk * 4 + lk) ^ (row & 7);
        b[nf] = *reinterpret_cast<const bf16x8*>(&Bs[row * 64 + ch * 8]);
      }
#pragma unroll
      for (int mf = 0; mf < 4; ++mf)
#pragma unroll
        for (int nf = 0; nf < 4; ++nf)
          acc[mf][nf] = __builtin_amdgcn_mfma_f32_16x16x32_bf16(a[mf], b[nf],
                                                                acc[mf][nf], 0, 0, 0);
    }
  }
  const float QSC = 0.125f * L2E;  // fold score-scale + log2(e) into Q
#pragma unroll
  for (int mf = 0; mf < 4; ++mf)
#pragma unroll
    for (int nf = 0; nf < 4; ++nf)
#pragma unroll
      for (int r = 0; r < 4; ++r) {
        int gr = m0 + wr + mf * 16 + lk * 4 + r;
        int gc = n0 + wc + nf * 16 + lr;
        float v = acc[mf][nf][r] + bias[gc];
        int b_ = gr >> 11, s = gr & 2047;
        int h = gc / 192, j = gc - h * 192;
        int part = j >> 6, d = j & 63;
        if (part == 0)
          Qo[((size_t)(b_ * 16 + h) * 2048 + s) * 64 + d] = f2bf(v * QSC);
        else if (part == 1)
          Ko[((size_t)(b_ * 16 + h) * 2048 + s) * 64 + d] = f2bf(v);
        else
          Vt[((size_t)(b_ * 16 + h) * 64 + d) * 2048 + s] = f2bf(v);
      }
}

// ---------------- flash attention, swapped-operand 32x32x16 ----------------
// Grid: bh(32) x qtile(16); block 256 = 4 waves; wave owns 32 q-rows.
__global__ __launch_bounds__(256) void attn2(
    const u16* __restrict__ Q, const u16* __restrict__ K,
    const u16* __restrict__ Vt, u16* __restrict__ ctx) {
  __shared__ __attribute__((aligned(16))) u16 Ks[2][64 * 64];
  __shared__ __attribute__((aligned(16))) u16 Vs[2][64 * 64];
  const int t = threadIdx.x;
  const int w = t >> 6, l = t & 63;
  const int lq = l & 31, hi = l >> 5;
  const int bh = blockIdx.x >> 4, qt = blockIdx.x & 15;
  const int b = bh >> 4, h = bh & 15;
  const u16* Qp = Q + (size_t)bh * (2048 * 64);
  const u16* Kp = K + (size_t)bh * (2048 * 64);
  const u16* Vp = Vt + (size_t)bh * (64 * 2048);
  const int q0w = qt * 128 + w * 32;

  const int srow = w * 16 + (l >> 3);
  const int sch = (l & 7) ^ ((l >> 3) & 7);

  bf16x8 qf[4];
#pragma unroll
  for (int i = 0; i < 4; ++i)
    qf[i] = *reinterpret_cast<const bf16x8*>(
        &Qp[(size_t)(q0w + lq) * 64 + i * 16 + hi * 8]);

  bf16x8 ones;
#pragma unroll
  for (int j = 0; j < 8; ++j) ones[j] = (short)0x3F80;  // bf16 1.0

  f32x16 o0 = {}, o1 = {}, osum = {};
  float mrun = -1e30f;

#define STG(bufi, kk0)                                                         \
  do {                                                                         \
    gll16(Kp + (size_t)((kk0) + srow) * 64 + sch * 8,                          \
          &Ks[bufi][(w * 16) * 64]);                                           \
    gll16(Kp + (size_t)((kk0) + srow + 8) * 64 + sch * 8,                      \
          &Ks[bufi][(w * 16 + 8) * 64]);                                       \
    gll16(Vp + (size_t)srow * 2048 + (kk0) + sch * 8,                          \
          &Vs[bufi][(w * 16) * 64]);                                           \
    gll16(Vp + (size_t)(srow + 8) * 2048 + (kk0) + sch * 8,                    \
          &Vs[bufi][(w * 16 + 8) * 64]);                                       \
  } while (0)

  // P fragment assembly: exchange word-pairs across the lane^32 split via
  // __shfl_xor (semantics-safe replacement for v_permlane32_swap_b32).
  // hi=0 lane needs [own W0, own W1, partner W0, partner W1] (k 0..7)
  // hi=1 lane needs [partner W2, partner W3, own W2, own W3] (k 8..15)
#define PVSTEP(pp, sub)                                                        \
  do {                                                                         \
    _Pragma("unroll")                                                          \
    for (int kb = 0; kb < 2; ++kb) {                                           \
      unsigned W0 = cvtpk(pp[8 * kb + 0], pp[8 * kb + 1]);                     \
      unsigned W1 = cvtpk(pp[8 * kb + 2], pp[8 * kb + 3]);                     \
      unsigned W2 = cvtpk(pp[8 * kb + 4], pp[8 * kb + 5]);                     \
      unsigned W3 = cvtpk(pp[8 * kb + 6], pp[8 * kb + 7]);                     \
      unsigned X0 = (unsigned)__shfl_xor((int)W0, 32);                         \
      unsigned X1 = (unsigned)__shfl_xor((int)W1, 32);                         \
      unsigned X2 = (unsigned)__shfl_xor((int)W2, 32);                         \
      unsigned X3 = (unsigned)__shfl_xor((int)W3, 32);                         \
      union { unsigned u[4]; bf16x8 v; } pu;                                   \
      pu.u[0] = hi ? X2 : W0;                                                  \
      pu.u[1] = hi ? X3 : W1;                                                  \
      pu.u[2] = hi ? W2 : X0;                                                  \
      pu.u[3] = hi ? W3 : X1;                                                  \
      const int ch = (((sub) * 4 + kb * 2 + hi) ^ (lq & 7)) * 8;               \
      bf16x8 v0 = *reinterpret_cast<const bf16x8*>(&VB[lq * 64 + ch]);         \
      o0 = __builtin_amdgcn_mfma_f32_32x32x16_bf16(v0, pu.v, o0, 0, 0, 0);     \
      bf16x8 v1 = *reinterpret_cast<const bf16x8*>(&VB[(32 + lq) * 64 + ch]);  \
      o1 = __builtin_amdgcn_mfma_f32_32x32x16_bf16(v1, pu.v, o1, 0, 0, 0);     \
      osum = __builtin_amdgcn_mfma_f32_32x32x16_bf16(ones, pu.v, osum, 0, 0, 0);\
    }                                                                          \
  } while (0)

  STG(0, 0);
  asm volatile("s_waitcnt vmcnt(0)");
  __syncthreads();

#pragma unroll 2
  for (int kt = 0; kt < 32; ++kt) {
    const int buf = kt & 1;
    if (kt < 31) { STG(buf ^ 1, (kt + 1) * 64); }
    const u16* KB = Ks[buf];
    const u16* VB = Vs[buf];

    // S^T = K Q^T : lane holds col q = lq, rows k = crow(reg,hi)(+32 for s1)
    f32x16 s0 = {}, s1 = {};
#pragma unroll
    for (int i = 0; i < 4; ++i) {
      const int sl = ((2 * i + hi) ^ (lq & 7)) * 8;
      bf16x8 k0f = *reinterpret_cast<const bf16x8*>(&KB[lq * 64 + sl]);
      s0 = __builtin_amdgcn_mfma_f32_32x32x16_bf16(k0f, qf[i], s0, 0, 0, 0);
      bf16x8 k1f = *reinterpret_cast<const bf16x8*>(&KB[(32 + lq) * 64 + sl]);
      s1 = __builtin_amdgcn_mfma_f32_32x32x16_bf16(k1f, qf[i], s1, 0, 0, 0);
    }

    // in-lane max over 32 values + partner-lane exchange (lane ^ 32)
    float mx[8];
#pragma unroll
    for (int r = 0; r < 8; ++r)
      mx[r] = fmaxf(fmaxf(s0[r], s0[r + 8]), fmaxf(s1[r], s1[r + 8]));
#pragma unroll
    for (int r = 0; r < 4; ++r) mx[r] = fmaxf(mx[r], mx[r + 4]);
    float tm = fmaxf(fmaxf(mx[0], mx[1]), fmaxf(mx[2], mx[3]));
    tm = fmaxf(tm, __shfl_xor(tm, 32));

    // deferred-max rescale (THR=8 in exp2 domain)
    if (!__all(tm - mrun <= 8.0f)) {
      float mnew = fmaxf(mrun, tm);
      float al = fexp2(mrun - mnew);
      mrun = mnew;
#pragma unroll
      for (int r = 0; r < 16; ++r) { o0[r] *= al; o1[r] *= al; }
      osum[0] *= al;
    }

    float p0[16], p1[16];
#pragma unroll
    for (int r = 0; r < 16; ++r) p0[r] = fexp2(s0[r] - mrun);
#pragma unroll
    for (int r = 0; r < 16; ++r) p1[r] = fexp2(s1[r] - mrun);

    PVSTEP(p0, 0);
    PVSTEP(p1, 1);

    asm volatile("s_waitcnt vmcnt(0)");
    __syncthreads();
  }
#undef STG
#undef PVSTEP

  // epilogue: normalize, pack pairs, store ctx[b][s=q][h*64+d]
  const float inv = 1.0f / osum[0];
  u16* cp = ctx + ((size_t)(b * 2048 + q0w + lq) * 1024 + h * 64);
#pragma unroll
  for (int m = 0; m < 8; ++m) {
    const int d = ((2 * m) & 3) + 8 * (m >> 1) + 4 * hi;
    unsigned wa = cvtpk(o0[2 * m] * inv, o0[2 * m + 1] * inv);
    *reinterpret_cast<unsigned*>(cp + d) = wa;
    unsigned wb = cvtpk(o1[2 * m] * inv, o1[2 * m + 1] * inv);
    *reinterpret_cast<unsigned*>(cp + 32 + d) = wb;
  }
}

// ---------------- dense GEMM (m97 structure): ctx[4096,1024]bf16 @ Bt[1024,1024] -> fp32 ----------------
__global__ __launch_bounds__(256) void gemm_dense(
    const u16* __restrict__ A, const u16* __restrict__ Bt,
    const float* __restrict__ bias, float* __restrict__ out) {
  __shared__ __attribute__((aligned(16))) u16 As[128 * 64];
  __shared__ __attribute__((aligned(16))) u16 Bs[128 * 64];
  const int t = threadIdx.x, w = t >> 6, l = t & 63;
  const int m0 = blockIdx.y * 128, n0 = blockIdx.x * 128;
  const int lr = l & 15, lk = l >> 4;
  const int wr = (w >> 1) * 64, wc = (w & 1) * 64;
  const int sr = l >> 3;
  const int sch = (l & 7) ^ sr;
  f32x4 acc[4][4] = {};

  for (int kt = 0; kt < 16; ++kt) {
    const int k0 = kt * 64;
    __syncthreads();
#pragma unroll
    for (int j = 0; j < 4; ++j) {
      const int row = w * 32 + j * 8 + sr;
      gll16(A + (size_t)(m0 + row) * 1024 + k0 + sch * 8, &As[(w * 32 + j * 8) * 64]);
      gll16(Bt + (size_t)(n0 + row) * 1024 + k0 + sch * 8, &Bs[(w * 32 + j * 8) * 64]);
    }
    asm volatile("s_waitcnt vmcnt(0)");
    __syncthreads();
#pragma unroll
    for (int kk = 0; kk < 2; ++kk) {
      bf16x8 a[4], b[4];
#pragma unroll
      for (int mf = 0; mf < 4; ++mf) {
        const int row = wr + mf * 16 + lr;
        const int ch = (kk * 4 + lk) ^ (row & 7);
        a[mf] = *reinterpret_cast<const bf16x8*>(&As[row * 64 + ch * 8]);
      }
#pragma unroll
      for (int nf = 0; nf < 4; ++nf) {
        const int row = wc + nf * 16 + lr;
        const int ch = (kk * 4 + lk) ^ (row & 7);
        b[nf] = *reinterpret_cast<const bf16x8*>(&Bs[row * 64 + ch * 8]);
      }
#pragma unroll
      for (int mf = 0; mf < 4; ++mf)
#pragma unroll
        for (int nf = 0; nf < 4; ++nf)
          acc[mf][nf] = __builtin_amdgcn_mfma_f32_16x16x32_bf16(a[mf], b[nf],
                                                                acc[mf][nf], 0, 0, 0);
    }
  }
#pragma unroll
  for (int mf = 0; mf < 4; ++mf)
#pragma unroll
    for (int nf = 0; nf < 4; ++nf)
#pragma unroll
      for (int r = 0; r < 4; ++r) {
        int gr = m0 + wr + mf * 16 + lk * 4 + r;
        int gc = n0 + wc + nf * 16 + lr;
        out[(size_t)gr * 1024 + gc] = acc[mf][nf][r] + bias[gc];
      }
}

extern "C" void kernel_launch(void* const* d_in, const int* in_sizes, int n_in,
                              void* d_out, int out_size, void* d_ws, size_t ws_size,
                              hipStream_t stream) {
  const float* hs = (const float*)d_in[0];       // [2,2048,1024]
  const float* w_qkv = (const float*)d_in[1];    // [1024,3072]
  const float* b_qkv = (const float*)d_in[2];    // [3072]
  const float* w_dense = (const float*)d_in[3];  // [1024,1024]
  const float* b_dense = (const float*)d_in[4];  // [1024]
  float* out = (float*)d_out;

  char* ws = (char*)d_ws;
  u16* hsb = (u16*)(ws);                  // 8 MB  [4096][1024]
  u16* wqkvT = (u16*)(ws + (8ll << 20));  // 6 MB  [3072][1024]
  u16* wdT = (u16*)(ws + (14ll << 20));   // 2 MB  [1024][1024]
  u16* Qb = (u16*)(ws + (16ll << 20));    // 8 MB  [2][16][2048][64] (pre-scaled)
  u16* Kb = (u16*)(ws + (24ll << 20));    // 8 MB
  u16* Vtb = (u16*)(ws + (32ll << 20));   // 8 MB  [2][16][64][2048]
  u16* ctx = (u16*)(ws + (40ll << 20));   // 8 MB  [4096][1024]

  cvt_bf16<<<dim3(2048), dim3(256), 0, stream>>>(hs, hsb, (4096 * 1024) / 4);
  transpose_cvt<<<dim3(96, 32), dim3(256), 0, stream>>>(w_qkv, wqkvT, 1024, 3072);
  transpose_cvt<<<dim3(32, 32), dim3(256), 0, stream>>>(w_dense, wdT, 1024, 1024);
  gemm_qkv<<<dim3(24, 32), dim3(256), 0, stream>>>(hsb, wqkvT, b_qkv, Qb, Kb, Vtb);
  attn2<<<dim3(512), dim3(256), 0, stream>>>(Qb, Kb, Vtb, ctx);
  gemm_dense<<<dim3(8, 32), dim3(256), 0, stream>>>(ctx, wdT, b_dense, out);
}

// Round 6
// 213.737 us; speedup vs baseline: 1.3093x; 1.0167x over previous
//
#include <hip/hip_runtime.h>

#define L2E 1.44269504088896f

typedef unsigned short u16;
typedef __attribute__((ext_vector_type(8))) short bf16x8;
typedef __attribute__((ext_vector_type(4))) float f32x4;
typedef __attribute__((ext_vector_type(16))) float f32x16;

__device__ __forceinline__ u16 f2bf(float x) {
  union { float f; unsigned u; } a; a.f = x;
  return (u16)((a.u + 0x7fffu + ((a.u >> 16) & 1u)) >> 16);
}

__device__ __forceinline__ unsigned cvtpk(float lo, float hi) {
  unsigned r;
  asm("v_cvt_pk_bf16_f32 %0, %1, %2" : "=v"(r) : "v"(lo), "v"(hi));
  return r;
}

__device__ __forceinline__ float fexp2(float x) {
  float r;
  asm("v_exp_f32 %0, %1" : "=v"(r) : "v"(x));
  return r;
}

__device__ __forceinline__ void gll16(const u16* g, u16* lds) {
  __builtin_amdgcn_global_load_lds(
      (const __attribute__((address_space(1))) unsigned int*)g,
      (__attribute__((address_space(3))) unsigned int*)lds, 16, 0, 0);
}

// ---------------- fp32 -> bf16 elementwise (x4 vectorized) ----------------
__global__ __launch_bounds__(256) void cvt_bf16(const float* __restrict__ in,
                                                u16* __restrict__ out, int n4) {
  int i = blockIdx.x * 256 + threadIdx.x;
  int stride = gridDim.x * 256;
  for (; i < n4; i += stride) {
    float4 v = reinterpret_cast<const float4*>(in)[i];
    ushort4 o;
    o.x = f2bf(v.x); o.y = f2bf(v.y); o.z = f2bf(v.z); o.w = f2bf(v.w);
    reinterpret_cast<ushort4*>(out)[i] = o;
  }
}

// ---------------- fp32 [K][N] -> bf16 [N][K] (tiled transpose) ----------------
__global__ __launch_bounds__(256) void transpose_cvt(const float* __restrict__ in,
                                                     u16* __restrict__ out,
                                                     int K, int N) {
  __shared__ float tile[32][33];
  int n0 = blockIdx.x * 32, k0 = blockIdx.y * 32;
  int tx = threadIdx.x & 31, ty = threadIdx.x >> 5;
  for (int r = ty; r < 32; r += 8)
    tile[r][tx] = in[(k0 + r) * N + n0 + tx];
  __syncthreads();
  for (int r = ty; r < 32; r += 8)
    out[(n0 + r) * K + k0 + tx] = f2bf(tile[tx][r]);
}

// ---------------- QKV GEMM (m97 structure): [4096,1024]bf16 @ Bt[3072,1024] ----------------
__global__ __launch_bounds__(256) void gemm_qkv(
    const u16* __restrict__ A, const u16* __restrict__ Bt,
    const float* __restrict__ bias,
    u16* __restrict__ Qo, u16* __restrict__ Ko, u16* __restrict__ Vt) {
  __shared__ __attribute__((aligned(16))) u16 As[128 * 64];
  __shared__ __attribute__((aligned(16))) u16 Bs[128 * 64];
  const int t = threadIdx.x, w = t >> 6, l = t & 63;
  const int m0 = blockIdx.y * 128, n0 = blockIdx.x * 128;
  const int lr = l & 15, lk = l >> 4;
  const int wr = (w >> 1) * 64, wc = (w & 1) * 64;
  const int sr = l >> 3;                 // 0..7
  const int sch = (l & 7) ^ sr;          // swizzled chunk for staging source
  f32x4 acc[4][4] = {};

  for (int kt = 0; kt < 16; ++kt) {
    const int k0 = kt * 64;
    __syncthreads();
#pragma unroll
    for (int j = 0; j < 4; ++j) {
      const int row = w * 32 + j * 8 + sr;
      gll16(A + (size_t)(m0 + row) * 1024 + k0 + sch * 8, &As[(w * 32 + j * 8) * 64]);
      gll16(Bt + (size_t)(n0 + row) * 1024 + k0 + sch * 8, &Bs[(w * 32 + j * 8) * 64]);
    }
    asm volatile("s_waitcnt vmcnt(0)");
    __syncthreads();
#pragma unroll
    for (int kk = 0; kk < 2; ++kk) {
      bf16x8 a[4], b[4];
#pragma unroll
      for (int mf = 0; mf < 4; ++mf) {
        const int row = wr + mf * 16 + lr;
        const int ch = (kk * 4 + lk) ^ (row & 7);
        a[mf] = *reinterpret_cast<const bf16x8*>(&As[row * 64 + ch * 8]);
      }
#pragma unroll
      for (int nf = 0; nf < 4; ++nf) {
        const int row = wc + nf * 16 + lr;
        const int ch = (kk * 4 + lk) ^ (row & 7);
        b[nf] = *reinterpret_cast<const bf16x8*>(&Bs[row * 64 + ch * 8]);
      }
#pragma unroll
      for (int mf = 0; mf < 4; ++mf)
#pragma unroll
        for (int nf = 0; nf < 4; ++nf)
          acc[mf][nf] = __builtin_amdgcn_mfma_f32_16x16x32_bf16(a[mf], b[nf],
                                                                acc[mf][nf], 0, 0, 0);
    }
  }
  const float QSC = 0.125f * L2E;  // fold score-scale + log2(e) into Q
#pragma unroll
  for (int mf = 0; mf < 4; ++mf)
#pragma unroll
    for (int nf = 0; nf < 4; ++nf) {
      const int gc = n0 + wc + nf * 16 + lr;
      const int h = gc / 192, j = gc - h * 192;
      const int part = j >> 6, d = j & 63;
      const float bv = bias[gc];
      const int gr0 = m0 + wr + mf * 16 + lk * 4;
      const int b_ = gr0 >> 11, s0 = gr0 & 2047;
      if (part == 2) {
        // pack 4 consecutive s into one 8B store: Vt[(b,h,d)][s0..s0+3]
        union { ushort4 s; unsigned u[2]; } pk;
        pk.u[0] = cvtpk(acc[mf][nf][0] + bv, acc[mf][nf][1] + bv);
        pk.u[1] = cvtpk(acc[mf][nf][2] + bv, acc[mf][nf][3] + bv);
        *reinterpret_cast<ushort4*>(
            &Vt[((size_t)(b_ * 16 + h) * 64 + d) * 2048 + s0]) = pk.s;
      } else if (part == 0) {
#pragma unroll
        for (int r = 0; r < 4; ++r)
          Qo[((size_t)(b_ * 16 + h) * 2048 + s0 + r) * 64 + d] =
              f2bf((acc[mf][nf][r] + bv) * QSC);
      } else {
#pragma unroll
        for (int r = 0; r < 4; ++r)
          Ko[((size_t)(b_ * 16 + h) * 2048 + s0 + r) * 64 + d] =
              f2bf(acc[mf][nf][r] + bv);
      }
    }
}

// ---------------- flash attention, swapped-operand 32x32x16 ----------------
// Grid: 512 blocks (XCD-chunked swizzle), block 256 = 4 waves; wave owns 32 q-rows.
__global__ __launch_bounds__(256) void attn2(
    const u16* __restrict__ Q, const u16* __restrict__ K,
    const u16* __restrict__ Vt, u16* __restrict__ ctx) {
  __shared__ __attribute__((aligned(16))) u16 Ks[2][64 * 64];
  __shared__ __attribute__((aligned(16))) u16 Vs[2][64 * 64];
  const int t = threadIdx.x;
  const int w = t >> 6, l = t & 63;
  const int lq = l & 31, hi = l >> 5;
  // bijective XCD-chunked swizzle: 512 blocks, 64 per XCD -> 4 bh per XCD L2
  const int bid = blockIdx.x;
  const int wg = (bid & 7) * 64 + (bid >> 3);
  const int bh = wg >> 4, qt = wg & 15;
  const int b = bh >> 4, h = bh & 15;
  const u16* Qp = Q + (size_t)bh * (2048 * 64);
  const u16* Kp = K + (size_t)bh * (2048 * 64);
  const u16* Vp = Vt + (size_t)bh * (64 * 2048);
  const int q0w = qt * 128 + w * 32;

  const int srow = w * 16 + (l >> 3);
  const int sch = (l & 7) ^ ((l >> 3) & 7);

  bf16x8 qf[4];
#pragma unroll
  for (int i = 0; i < 4; ++i)
    qf[i] = *reinterpret_cast<const bf16x8*>(
        &Qp[(size_t)(q0w + lq) * 64 + i * 16 + hi * 8]);

  bf16x8 ones;
#pragma unroll
  for (int j = 0; j < 8; ++j) ones[j] = (short)0x3F80;  // bf16 1.0

  f32x16 o0 = {}, o1 = {}, osum = {};
  float mrun = -1e30f;

#define STG(bufi, kk0)                                                         \
  do {                                                                         \
    gll16(Kp + (size_t)((kk0) + srow) * 64 + sch * 8,                          \
          &Ks[bufi][(w * 16) * 64]);                                           \
    gll16(Kp + (size_t)((kk0) + srow + 8) * 64 + sch * 8,                      \
          &Ks[bufi][(w * 16 + 8) * 64]);                                       \
    gll16(Vp + (size_t)srow * 2048 + (kk0) + sch * 8,                          \
          &Vs[bufi][(w * 16) * 64]);                                           \
    gll16(Vp + (size_t)(srow + 8) * 2048 + (kk0) + sch * 8,                    \
          &Vs[bufi][(w * 16 + 8) * 64]);                                       \
  } while (0)

  // P fragment assembly: exchange word-pairs across the lane^32 split via
  // __shfl_xor. hi=0 lane needs [own W0, own W1, partner W0, partner W1];
  // hi=1 lane needs [partner W2, partner W3, own W2, own W3].
#define PVSTEP(pp, sub)                                                        \
  do {                                                                         \
    _Pragma("unroll")                                                          \
    for (int kb = 0; kb < 2; ++kb) {                                           \
      unsigned W0 = cvtpk(pp[8 * kb + 0], pp[8 * kb + 1]);                     \
      unsigned W1 = cvtpk(pp[8 * kb + 2], pp[8 * kb + 3]);                     \
      unsigned W2 = cvtpk(pp[8 * kb + 4], pp[8 * kb + 5]);                     \
      unsigned W3 = cvtpk(pp[8 * kb + 6], pp[8 * kb + 7]);                     \
      unsigned X0 = (unsigned)__shfl_xor((int)W0, 32);                         \
      unsigned X1 = (unsigned)__shfl_xor((int)W1, 32);                         \
      unsigned X2 = (unsigned)__shfl_xor((int)W2, 32);                         \
      unsigned X3 = (unsigned)__shfl_xor((int)W3, 32);                         \
      union { unsigned u[4]; bf16x8 v; } pu;                                   \
      pu.u[0] = hi ? X2 : W0;                                                  \
      pu.u[1] = hi ? X3 : W1;                                                  \
      pu.u[2] = hi ? W2 : X0;                                                  \
      pu.u[3] = hi ? W3 : X1;                                                  \
      const int ch = (((sub) * 4 + kb * 2 + hi) ^ (lq & 7)) * 8;               \
      bf16x8 v0 = *reinterpret_cast<const bf16x8*>(&VB[lq * 64 + ch]);         \
      o0 = __builtin_amdgcn_mfma_f32_32x32x16_bf16(v0, pu.v, o0, 0, 0, 0);     \
      bf16x8 v1 = *reinterpret_cast<const bf16x8*>(&VB[(32 + lq) * 64 + ch]);  \
      o1 = __builtin_amdgcn_mfma_f32_32x32x16_bf16(v1, pu.v, o1, 0, 0, 0);     \
      osum = __builtin_amdgcn_mfma_f32_32x32x16_bf16(ones, pu.v, osum, 0, 0, 0);\
    }                                                                          \
  } while (0)

  STG(0, 0);
  asm volatile("s_waitcnt vmcnt(0)");
  __syncthreads();

#pragma unroll 2
  for (int kt = 0; kt < 32; ++kt) {
    const int buf = kt & 1;
    if (kt < 31) { STG(buf ^ 1, (kt + 1) * 64); }
    const u16* KB = Ks[buf];
    const u16* VB = Vs[buf];

    // S^T = K Q^T : lane holds col q = lq, rows k = crow(reg,hi)(+32 for s1)
    f32x16 s0 = {}, s1 = {};
#pragma unroll
    for (int i = 0; i < 4; ++i) {
      const int sl = ((2 * i + hi) ^ (lq & 7)) * 8;
      bf16x8 k0f = *reinterpret_cast<const bf16x8*>(&KB[lq * 64 + sl]);
      s0 = __builtin_amdgcn_mfma_f32_32x32x16_bf16(k0f, qf[i], s0, 0, 0, 0);
      bf16x8 k1f = *reinterpret_cast<const bf16x8*>(&KB[(32 + lq) * 64 + sl]);
      s1 = __builtin_amdgcn_mfma_f32_32x32x16_bf16(k1f, qf[i], s1, 0, 0, 0);
    }

    // in-lane max over 32 values + partner-lane exchange (lane ^ 32)
    float mx[8];
#pragma unroll
    for (int r = 0; r < 8; ++r)
      mx[r] = fmaxf(fmaxf(s0[r], s0[r + 8]), fmaxf(s1[r], s1[r + 8]));
#pragma unroll
    for (int r = 0; r < 4; ++r) mx[r] = fmaxf(mx[r], mx[r + 4]);
    float tm = fmaxf(fmaxf(mx[0], mx[1]), fmaxf(mx[2], mx[3]));
    tm = fmaxf(tm, __shfl_xor(tm, 32));

    // deferred-max rescale (THR=8 in exp2 domain)
    if (!__all(tm - mrun <= 8.0f)) {
      float mnew = fmaxf(mrun, tm);
      float al = fexp2(mrun - mnew);
      mrun = mnew;
#pragma unroll
      for (int r = 0; r < 16; ++r) { o0[r] *= al; o1[r] *= al; }
      osum[0] *= al;
    }

    float p0[16], p1[16];
#pragma unroll
    for (int r = 0; r < 16; ++r) p0[r] = fexp2(s0[r] - mrun);
#pragma unroll
    for (int r = 0; r < 16; ++r) p1[r] = fexp2(s1[r] - mrun);

    PVSTEP(p0, 0);
    PVSTEP(p1, 1);

    asm volatile("s_waitcnt vmcnt(0)");
    __syncthreads();
  }
#undef STG
#undef PVSTEP

  // epilogue: normalize, pack quads (4 consecutive d), store ctx[b][s=q][h*64+d]
  const float inv = 1.0f / osum[0];
  u16* cp = ctx + ((size_t)(b * 2048 + q0w + lq) * 1024 + h * 64);
#pragma unroll
  for (int a = 0; a < 4; ++a) {
    const int d = 8 * a + 4 * hi;
    union { ushort4 s; unsigned u[2]; } pk;
    pk.u[0] = cvtpk(o0[4 * a + 0] * inv, o0[4 * a + 1] * inv);
    pk.u[1] = cvtpk(o0[4 * a + 2] * inv, o0[4 * a + 3] * inv);
    *reinterpret_cast<ushort4*>(cp + d) = pk.s;
    pk.u[0] = cvtpk(o1[4 * a + 0] * inv, o1[4 * a + 1] * inv);
    pk.u[1] = cvtpk(o1[4 * a + 2] * inv, o1[4 * a + 3] * inv);
    *reinterpret_cast<ushort4*>(cp + 32 + d) = pk.s;
  }
}

// ---------------- dense GEMM (m97 structure): ctx[4096,1024]bf16 @ Bt[1024,1024] -> fp32 ----------------
__global__ __launch_bounds__(256) void gemm_dense(
    const u16* __restrict__ A, const u16* __restrict__ Bt,
    const float* __restrict__ bias, float* __restrict__ out) {
  __shared__ __attribute__((aligned(16))) u16 As[128 * 64];
  __shared__ __attribute__((aligned(16))) u16 Bs[128 * 64];
  const int t = threadIdx.x, w = t >> 6, l = t & 63;
  const int m0 = blockIdx.y * 128, n0 = blockIdx.x * 128;
  const int lr = l & 15, lk = l >> 4;
  const int wr = (w >> 1) * 64, wc = (w & 1) * 64;
  const int sr = l >> 3;
  const int sch = (l & 7) ^ sr;
  f32x4 acc[4][4] = {};

  for (int kt = 0; kt < 16; ++kt) {
    const int k0 = kt * 64;
    __syncthreads();
#pragma unroll
    for (int j = 0; j < 4; ++j) {
      const int row = w * 32 + j * 8 + sr;
      gll16(A + (size_t)(m0 + row) * 1024 + k0 + sch * 8, &As[(w * 32 + j * 8) * 64]);
      gll16(Bt + (size_t)(n0 + row) * 1024 + k0 + sch * 8, &Bs[(w * 32 + j * 8) * 64]);
    }
    asm volatile("s_waitcnt vmcnt(0)");
    __syncthreads();
#pragma unroll
    for (int kk = 0; kk < 2; ++kk) {
      bf16x8 a[4], b[4];
#pragma unroll
      for (int mf = 0; mf < 4; ++mf) {
        const int row = wr + mf * 16 + lr;
        const int ch = (kk * 4 + lk) ^ (row & 7);
        a[mf] = *reinterpret_cast<const bf16x8*>(&As[row * 64 + ch * 8]);
      }
#pragma unroll
      for (int nf = 0; nf < 4; ++nf) {
        const int row = wc + nf * 16 + lr;
        const int ch = (kk * 4 + lk) ^ (row & 7);
        b[nf] = *reinterpret_cast<const bf16x8*>(&Bs[row * 64 + ch * 8]);
      }
#pragma unroll
      for (int mf = 0; mf < 4; ++mf)
#pragma unroll
        for (int nf = 0; nf < 4; ++nf)
          acc[mf][nf] = __builtin_amdgcn_mfma_f32_16x16x32_bf16(a[mf], b[nf],
                                                                acc[mf][nf], 0, 0, 0);
    }
  }
#pragma unroll
  for (int mf = 0; mf < 4; ++mf)
#pragma unroll
    for (int nf = 0; nf < 4; ++nf)
#pragma unroll
      for (int r = 0; r < 4; ++r) {
        int gr = m0 + wr + mf * 16 + lk * 4 + r;
        int gc = n0 + wc + nf * 16 + lr;
        out[(size_t)gr * 1024 + gc] = acc[mf][nf][r] + bias[gc];
      }
}

extern "C" void kernel_launch(void* const* d_in, const int* in_sizes, int n_in,
                              void* d_out, int out_size, void* d_ws, size_t ws_size,
                              hipStream_t stream) {
  const float* hs = (const float*)d_in[0];       // [2,2048,1024]
  const float* w_qkv = (const float*)d_in[1];    // [1024,3072]
  const float* b_qkv = (const float*)d_in[2];    // [3072]
  const float* w_dense = (const float*)d_in[3];  // [1024,1024]
  const float* b_dense = (const float*)d_in[4];  // [1024]
  float* out = (float*)d_out;

  char* ws = (char*)d_ws;
  u16* hsb = (u16*)(ws);                  // 8 MB  [4096][1024]
  u16* wqkvT = (u16*)(ws + (8ll << 20));  // 6 MB  [3072][1024]
  u16* wdT = (u16*)(ws + (14ll << 20));   // 2 MB  [1024][1024]
  u16* Qb = (u16*)(ws + (16ll << 20));    // 8 MB  [2][16][2048][64] (pre-scaled)
  u16* Kb = (u16*)(ws + (24ll << 20));    // 8 MB
  u16* Vtb = (u16*)(ws + (32ll << 20));   // 8 MB  [2][16][64][2048]
  u16* ctx = (u16*)(ws + (40ll << 20));   // 8 MB  [4096][1024]

  cvt_bf16<<<dim3(2048), dim3(256), 0, stream>>>(hs, hsb, (4096 * 1024) / 4);
  transpose_cvt<<<dim3(96, 32), dim3(256), 0, stream>>>(w_qkv, wqkvT, 1024, 3072);
  transpose_cvt<<<dim3(32, 32), dim3(256), 0, stream>>>(w_dense, wdT, 1024, 1024);
  gemm_qkv<<<dim3(24, 32), dim3(256), 0, stream>>>(hsb, wqkvT, b_qkv, Qb, Kb, Vtb);
  attn2<<<dim3(512), dim3(256), 0, stream>>>(Qb, Kb, Vtb, ctx);
  gemm_dense<<<dim3(8, 32), dim3(256), 0, stream>>>(ctx, wdT, b_dense, out);
}

// Round 9
// 203.572 us; speedup vs baseline: 1.3747x; 1.0499x over previous
//
#include <hip/hip_runtime.h>

#define L2E 1.44269504088896f

typedef unsigned short u16;
typedef __attribute__((ext_vector_type(8))) short bf16x8;
typedef __attribute__((ext_vector_type(4))) float f32x4;
typedef __attribute__((ext_vector_type(16))) float f32x16;

__device__ __forceinline__ u16 f2bf(float x) {
  union { float f; unsigned u; } a; a.f = x;
  return (u16)((a.u + 0x7fffu + ((a.u >> 16) & 1u)) >> 16);
}

__device__ __forceinline__ unsigned cvtpk(float lo, float hi) {
  unsigned r;
  asm("v_cvt_pk_bf16_f32 %0, %1, %2" : "=v"(r) : "v"(lo), "v"(hi));
  return r;
}

__device__ __forceinline__ float fexp2(float x) {
  float r;
  asm("v_exp_f32 %0, %1" : "=v"(r) : "v"(x));
  return r;
}

__device__ __forceinline__ void gll16(const u16* g, u16* lds) {
  __builtin_amdgcn_global_load_lds(
      (const __attribute__((address_space(1))) unsigned int*)g,
      (__attribute__((address_space(3))) unsigned int*)lds, 16, 0, 0);
}

// ---------------- fp32 -> bf16 elementwise (x4 vectorized) ----------------
__global__ __launch_bounds__(256) void cvt_bf16(const float* __restrict__ in,
                                                u16* __restrict__ out, int n4) {
  int i = blockIdx.x * 256 + threadIdx.x;
  int stride = gridDim.x * 256;
  for (; i < n4; i += stride) {
    float4 v = reinterpret_cast<const float4*>(in)[i];
    ushort4 o;
    o.x = f2bf(v.x); o.y = f2bf(v.y); o.z = f2bf(v.z); o.w = f2bf(v.w);
    reinterpret_cast<ushort4*>(out)[i] = o;
  }
}

// ---------------- fp32 [K][N] -> bf16 [N][K] (tiled transpose) ----------------
__global__ __launch_bounds__(256) void transpose_cvt(const float* __restrict__ in,
                                                     u16* __restrict__ out,
                                                     int K, int N) {
  __shared__ float tile[32][33];
  int n0 = blockIdx.x * 32, k0 = blockIdx.y * 32;
  int tx = threadIdx.x & 31, ty = threadIdx.x >> 5;
  for (int r = ty; r < 32; r += 8)
    tile[r][tx] = in[(k0 + r) * N + n0 + tx];
  __syncthreads();
  for (int r = ty; r < 32; r += 8)
    out[(n0 + r) * K + k0 + tx] = f2bf(tile[tx][r]);
}

// ---------------- QKV GEMM: dbuf + counted vmcnt (T3/T4 2-phase) ----------------
__global__ __launch_bounds__(256) void gemm_qkv(
    const u16* __restrict__ A, const u16* __restrict__ Bt,
    const float* __restrict__ bias,
    u16* __restrict__ Qo, u16* __restrict__ Ko, u16* __restrict__ Vt) {
  __shared__ __attribute__((aligned(16))) u16 As[2][128 * 64];
  __shared__ __attribute__((aligned(16))) u16 Bs[2][128 * 64];
  const int t = threadIdx.x, w = t >> 6, l = t & 63;
  const int m0 = blockIdx.y * 128, n0 = blockIdx.x * 128;
  const int lr = l & 15, lk = l >> 4;
  const int wr = (w >> 1) * 64, wc = (w & 1) * 64;
  const int sr = l >> 3;                 // 0..7
  const int sch = (l & 7) ^ sr;          // swizzled chunk for staging source
  f32x4 acc[4][4] = {};

#define QSTAGE(bi, k0)                                                        \
  do {                                                                        \
    _Pragma("unroll")                                                         \
    for (int j = 0; j < 4; ++j) {                                             \
      const int rb = w * 32 + j * 8;                                          \
      gll16(A + (size_t)(m0 + rb + sr) * 1024 + (k0) + sch * 8,               \
            &As[bi][rb * 64]);                                                \
      gll16(Bt + (size_t)(n0 + rb + sr) * 1024 + (k0) + sch * 8,              \
            &Bs[bi][rb * 64]);                                                \
    }                                                                         \
  } while (0)

  QSTAGE(0, 0);
  for (int kt = 0; kt < 16; ++kt) {
    const int buf = kt & 1;
    if (kt < 15) {
      QSTAGE(buf ^ 1, (kt + 1) * 64);
      asm volatile("s_waitcnt vmcnt(8)" ::: "memory");  // current tile landed
    } else {
      asm volatile("s_waitcnt vmcnt(0)" ::: "memory");
    }
    __builtin_amdgcn_s_barrier();
    const u16* Asb = As[buf];
    const u16* Bsb = Bs[buf];
#pragma unroll
    for (int kk = 0; kk < 2; ++kk) {
      bf16x8 a[4], b[4];
#pragma unroll
      for (int mf = 0; mf < 4; ++mf) {
        const int row = wr + mf * 16 + lr;
        const int ch = (kk * 4 + lk) ^ (row & 7);
        a[mf] = *reinterpret_cast<const bf16x8*>(&Asb[row * 64 + ch * 8]);
      }
#pragma unroll
      for (int nf = 0; nf < 4; ++nf) {
        const int row = wc + nf * 16 + lr;
        const int ch = (kk * 4 + lk) ^ (row & 7);
        b[nf] = *reinterpret_cast<const bf16x8*>(&Bsb[row * 64 + ch * 8]);
      }
#pragma unroll
      for (int mf = 0; mf < 4; ++mf)
#pragma unroll
        for (int nf = 0; nf < 4; ++nf)
          acc[mf][nf] = __builtin_amdgcn_mfma_f32_16x16x32_bf16(a[mf], b[nf],
                                                                acc[mf][nf], 0, 0, 0);
    }
    asm volatile("" ::: "memory");
    __builtin_amdgcn_s_barrier();  // readers done before next STAGE overwrites
  }
#undef QSTAGE

  const float QSC = 0.125f * L2E;  // fold score-scale + log2(e) into Q
#pragma unroll
  for (int mf = 0; mf < 4; ++mf)
#pragma unroll
    for (int nf = 0; nf < 4; ++nf) {
      const int gc = n0 + wc + nf * 16 + lr;
      const int h = gc / 192, j = gc - h * 192;
      const int part = j >> 6, d = j & 63;
      const float bv = bias[gc];
      const int gr0 = m0 + wr + mf * 16 + lk * 4;
      const int b_ = gr0 >> 11, s0 = gr0 & 2047;
      if (part == 2) {
        union { ushort4 s; unsigned u[2]; } pk;
        pk.u[0] = cvtpk(acc[mf][nf][0] + bv, acc[mf][nf][1] + bv);
        pk.u[1] = cvtpk(acc[mf][nf][2] + bv, acc[mf][nf][3] + bv);
        *reinterpret_cast<ushort4*>(
            &Vt[((size_t)(b_ * 16 + h) * 64 + d) * 2048 + s0]) = pk.s;
      } else if (part == 0) {
#pragma unroll
        for (int r = 0; r < 4; ++r)
          Qo[((size_t)(b_ * 16 + h) * 2048 + s0 + r) * 64 + d] =
              f2bf((acc[mf][nf][r] + bv) * QSC);
      } else {
#pragma unroll
        for (int r = 0; r < 4; ++r)
          Ko[((size_t)(b_ * 16 + h) * 2048 + s0 + r) * 64 + d] =
              f2bf(acc[mf][nf][r] + bv);
      }
    }
}

// ---------------- flash attention, swapped-operand 32x32x16, counted vmcnt ----------------
// Grid: 512 blocks (XCD-chunked swizzle), block 256 = 4 waves; wave owns 32 q-rows.
__global__ __launch_bounds__(256) void attn2(
    const u16* __restrict__ Q, const u16* __restrict__ K,
    const u16* __restrict__ Vt, u16* __restrict__ ctx) {
  __shared__ __attribute__((aligned(16))) u16 Ks[2][64 * 64];
  __shared__ __attribute__((aligned(16))) u16 Vs[2][64 * 64];
  const int t = threadIdx.x;
  const int w = t >> 6, l = t & 63;
  const int lq = l & 31, hi = l >> 5;
  const int bid = blockIdx.x;
  const int wg = (bid & 7) * 64 + (bid >> 3);
  const int bh = wg >> 4, qt = wg & 15;
  const int b = bh >> 4, h = bh & 15;
  const u16* Qp = Q + (size_t)bh * (2048 * 64);
  const u16* Kp = K + (size_t)bh * (2048 * 64);
  const u16* Vp = Vt + (size_t)bh * (64 * 2048);
  const int q0w = qt * 128 + w * 32;

  const int srow = w * 16 + (l >> 3);
  const int sch = (l & 7) ^ ((l >> 3) & 7);

  bf16x8 qf[4];
#pragma unroll
  for (int i = 0; i < 4; ++i)
    qf[i] = *reinterpret_cast<const bf16x8*>(
        &Qp[(size_t)(q0w + lq) * 64 + i * 16 + hi * 8]);

  bf16x8 ones;
#pragma unroll
  for (int j = 0; j < 8; ++j) ones[j] = (short)0x3F80;  // bf16 1.0

  f32x16 o0 = {}, o1 = {}, osum = {};
  float mrun = -1e30f;

#define STG(bufi, kk0)                                                         \
  do {                                                                         \
    gll16(Kp + (size_t)((kk0) + srow) * 64 + sch * 8,                          \
          &Ks[bufi][(w * 16) * 64]);                                           \
    gll16(Kp + (size_t)((kk0) + srow + 8) * 64 + sch * 8,                      \
          &Ks[bufi][(w * 16 + 8) * 64]);                                       \
    gll16(Vp + (size_t)srow * 2048 + (kk0) + sch * 8,                          \
          &Vs[bufi][(w * 16) * 64]);                                           \
    gll16(Vp + (size_t)(srow + 8) * 2048 + (kk0) + sch * 8,                    \
          &Vs[bufi][(w * 16 + 8) * 64]);                                       \
  } while (0)

#define PVSTEP(pp, sub)                                                        \
  do {                                                                         \
    _Pragma("unroll")                                                          \
    for (int kb = 0; kb < 2; ++kb) {                                           \
      unsigned W0 = cvtpk(pp[8 * kb + 0], pp[8 * kb + 1]);                     \
      unsigned W1 = cvtpk(pp[8 * kb + 2], pp[8 * kb + 3]);                     \
      unsigned W2 = cvtpk(pp[8 * kb + 4], pp[8 * kb + 5]);                     \
      unsigned W3 = cvtpk(pp[8 * kb + 6], pp[8 * kb + 7]);                     \
      unsigned X0 = (unsigned)__shfl_xor((int)W0, 32);                         \
      unsigned X1 = (unsigned)__shfl_xor((int)W1, 32);                         \
      unsigned X2 = (unsigned)__shfl_xor((int)W2, 32);                         \
      unsigned X3 = (unsigned)__shfl_xor((int)W3, 32);                         \
      union { unsigned u[4]; bf16x8 v; } pu;                                   \
      pu.u[0] = hi ? X2 : W0;                                                  \
      pu.u[1] = hi ? X3 : W1;                                                  \
      pu.u[2] = hi ? W2 : X0;                                                  \
      pu.u[3] = hi ? W3 : X1;                                                  \
      const int ch = (((sub) * 4 + kb * 2 + hi) ^ (lq & 7)) * 8;               \
      bf16x8 v0 = *reinterpret_cast<const bf16x8*>(&VB[lq * 64 + ch]);         \
      o0 = __builtin_amdgcn_mfma_f32_32x32x16_bf16(v0, pu.v, o0, 0, 0, 0);     \
      bf16x8 v1 = *reinterpret_cast<const bf16x8*>(&VB[(32 + lq) * 64 + ch]);  \
      o1 = __builtin_amdgcn_mfma_f32_32x32x16_bf16(v1, pu.v, o1, 0, 0, 0);     \
      osum = __builtin_amdgcn_mfma_f32_32x32x16_bf16(ones, pu.v, osum, 0, 0, 0);\
    }                                                                          \
  } while (0)

  STG(0, 0);

#pragma unroll 2
  for (int kt = 0; kt < 32; ++kt) {
    const int buf = kt & 1;
    if (kt < 31) {
      STG(buf ^ 1, (kt + 1) * 64);
      asm volatile("s_waitcnt vmcnt(4)" ::: "memory");  // current tile landed
    } else {
      asm volatile("s_waitcnt vmcnt(0)" ::: "memory");
    }
    __builtin_amdgcn_s_barrier();
    const u16* KB = Ks[buf];
    const u16* VB = Vs[buf];

    // S^T = K Q^T : lane holds col q = lq, rows k = crow(reg,hi)(+32 for s1)
    f32x16 s0 = {}, s1 = {};
#pragma unroll
    for (int i = 0; i < 4; ++i) {
      const int sl = ((2 * i + hi) ^ (lq & 7)) * 8;
      bf16x8 k0f = *reinterpret_cast<const bf16x8*>(&KB[lq * 64 + sl]);
      s0 = __builtin_amdgcn_mfma_f32_32x32x16_bf16(k0f, qf[i], s0, 0, 0, 0);
      bf16x8 k1f = *reinterpret_cast<const bf16x8*>(&KB[(32 + lq) * 64 + sl]);
      s1 = __builtin_amdgcn_mfma_f32_32x32x16_bf16(k1f, qf[i], s1, 0, 0, 0);
    }

    // in-lane max over 32 values + partner-lane exchange (lane ^ 32)
    float mx[8];
#pragma unroll
    for (int r = 0; r < 8; ++r)
      mx[r] = fmaxf(fmaxf(s0[r], s0[r + 8]), fmaxf(s1[r], s1[r + 8]));
#pragma unroll
    for (int r = 0; r < 4; ++r) mx[r] = fmaxf(mx[r], mx[r + 4]);
    float tm = fmaxf(fmaxf(mx[0], mx[1]), fmaxf(mx[2], mx[3]));
    tm = fmaxf(tm, __shfl_xor(tm, 32));

    // deferred-max rescale (THR=8 in exp2 domain)
    if (!__all(tm - mrun <= 8.0f)) {
      float mnew = fmaxf(mrun, tm);
      float al = fexp2(mrun - mnew);
      mrun = mnew;
#pragma unroll
      for (int r = 0; r < 16; ++r) { o0[r] *= al; o1[r] *= al; }
      osum[0] *= al;
    }

    float p0[16], p1[16];
#pragma unroll
    for (int r = 0; r < 16; ++r) p0[r] = fexp2(s0[r] - mrun);
#pragma unroll
    for (int r = 0; r < 16; ++r) p1[r] = fexp2(s1[r] - mrun);

    PVSTEP(p0, 0);
    PVSTEP(p1, 1);

    asm volatile("" ::: "memory");
    __builtin_amdgcn_s_barrier();  // readers done before next STG overwrites
  }
#undef STG
#undef PVSTEP

  // epilogue: normalize, pack quads (4 consecutive d), store ctx[b][s=q][h*64+d]
  const float inv = 1.0f / osum[0];
  u16* cp = ctx + ((size_t)(b * 2048 + q0w + lq) * 1024 + h * 64);
#pragma unroll
  for (int a = 0; a < 4; ++a) {
    const int d = 8 * a + 4 * hi;
    union { ushort4 s; unsigned u[2]; } pk;
    pk.u[0] = cvtpk(o0[4 * a + 0] * inv, o0[4 * a + 1] * inv);
    pk.u[1] = cvtpk(o0[4 * a + 2] * inv, o0[4 * a + 3] * inv);
    *reinterpret_cast<ushort4*>(cp + d) = pk.s;
    pk.u[0] = cvtpk(o1[4 * a + 0] * inv, o1[4 * a + 1] * inv);
    pk.u[1] = cvtpk(o1[4 * a + 2] * inv, o1[4 * a + 3] * inv);
    *reinterpret_cast<ushort4*>(cp + 32 + d) = pk.s;
  }
}

// ---------------- dense GEMM: 128x64 tiles, dbuf + counted vmcnt -> fp32 ----------------
__global__ __launch_bounds__(256) void gemm_dense(
    const u16* __restrict__ A, const u16* __restrict__ Bt,
    const float* __restrict__ bias, float* __restrict__ out) {
  __shared__ __attribute__((aligned(16))) u16 As[2][128 * 64];
  __shared__ __attribute__((aligned(16))) u16 Bs[2][64 * 64];
  const int t = threadIdx.x, w = t >> 6, l = t & 63;
  const int m0 = blockIdx.y * 128, n0 = blockIdx.x * 64;
  const int lr = l & 15, lk = l >> 4;
  const int wr = (w >> 1) * 64, wc = (w & 1) * 32;
  const int sr = l >> 3;
  const int sch = (l & 7) ^ sr;
  f32x4 acc[4][2] = {};

#define DSTAGE(bi, k0)                                                        \
  do {                                                                        \
    _Pragma("unroll")                                                         \
    for (int j = 0; j < 4; ++j) {                                             \
      const int rb = w * 32 + j * 8;                                          \
      gll16(A + (size_t)(m0 + rb + sr) * 1024 + (k0) + sch * 8,               \
            &As[bi][rb * 64]);                                                \
    }                                                                         \
    _Pragma("unroll")                                                         \
    for (int j = 0; j < 2; ++j) {                                             \
      const int rb = w * 16 + j * 8;                                          \
      gll16(Bt + (size_t)(n0 + rb + sr) * 1024 + (k0) + sch * 8,              \
            &Bs[bi][rb * 64]);                                                \
    }                                                                         \
  } while (0)

  DSTAGE(0, 0);
  for (int kt = 0; kt < 16; ++kt) {
    const int buf = kt & 1;
    if (kt < 15) {
      DSTAGE(buf ^ 1, (kt + 1) * 64);
      asm volatile("s_waitcnt vmcnt(6)" ::: "memory");
    } else {
      asm volatile("s_waitcnt vmcnt(0)" ::: "memory");
    }
    __builtin_amdgcn_s_barrier();
    const u16* Asb = As[buf];
    const u16* Bsb = Bs[buf];
#pragma unroll
    for (int kk = 0; kk < 2; ++kk) {
      bf16x8 a[4], b[2];
#pragma unroll
      for (int mf = 0; mf < 4; ++mf) {
        const int row = wr + mf * 16 + lr;
        const int ch = (kk * 4 + lk) ^ (row & 7);
        a[mf] = *reinterpret_cast<const bf16x8*>(&Asb[row * 64 + ch * 8]);
      }
#pragma unroll
      for (int nf = 0; nf < 2; ++nf) {
        const int row = wc + nf * 16 + lr;
        const int ch = (kk * 4 + lk) ^ (row & 7);
        b[nf] = *reinterpret_cast<const bf16x8*>(&Bsb[row * 64 + ch * 8]);
      }
#pragma unroll
      for (int mf = 0; mf < 4; ++mf)
#pragma unroll
        for (int nf = 0; nf < 2; ++nf)
          acc[mf][nf] = __builtin_amdgcn_mfma_f32_16x16x32_bf16(a[mf], b[nf],
                                                                acc[mf][nf], 0, 0, 0);
    }
    asm volatile("" ::: "memory");
    __builtin_amdgcn_s_barrier();
  }
#undef DSTAGE

#pragma unroll
  for (int mf = 0; mf < 4; ++mf)
#pragma unroll
    for (int nf = 0; nf < 2; ++nf)
#pragma unroll
      for (int r = 0; r < 4; ++r) {
        int gr = m0 + wr + mf * 16 + lk * 4 + r;
        int gc = n0 + wc + nf * 16 + lr;
        out[(size_t)gr * 1024 + gc] = acc[mf][nf][r] + bias[gc];
      }
}

extern "C" void kernel_launch(void* const* d_in, const int* in_sizes, int n_in,
                              void* d_out, int out_size, void* d_ws, size_t ws_size,
                              hipStream_t stream) {
  const float* hs = (const float*)d_in[0];       // [2,2048,1024]
  const float* w_qkv = (const float*)d_in[1];    // [1024,3072]
  const float* b_qkv = (const float*)d_in[2];    // [3072]
  const float* w_dense = (const float*)d_in[3];  // [1024,1024]
  const float* b_dense = (const float*)d_in[4];  // [1024]
  float* out = (float*)d_out;

  char* ws = (char*)d_ws;
  u16* hsb = (u16*)(ws);                  // 8 MB  [4096][1024]
  u16* wqkvT = (u16*)(ws + (8ll << 20));  // 6 MB  [3072][1024]
  u16* wdT = (u16*)(ws + (14ll << 20));   // 2 MB  [1024][1024]
  u16* Qb = (u16*)(ws + (16ll << 20));    // 8 MB  [2][16][2048][64] (pre-scaled)
  u16* Kb = (u16*)(ws + (24ll << 20));    // 8 MB
  u16* Vtb = (u16*)(ws + (32ll << 20));   // 8 MB  [2][16][64][2048]
  u16* ctx = (u16*)(ws + (40ll << 20));   // 8 MB  [4096][1024]

  cvt_bf16<<<dim3(2048), dim3(256), 0, stream>>>(hs, hsb, (4096 * 1024) / 4);
  transpose_cvt<<<dim3(96, 32), dim3(256), 0, stream>>>(w_qkv, wqkvT, 1024, 3072);
  transpose_cvt<<<dim3(32, 32), dim3(256), 0, stream>>>(w_dense, wdT, 1024, 1024);
  gemm_qkv<<<dim3(24, 32), dim3(256), 0, stream>>>(hsb, wqkvT, b_qkv, Qb, Kb, Vtb);
  attn2<<<dim3(512), dim3(256), 0, stream>>>(Qb, Kb, Vtb, ctx);
  gemm_dense<<<dim3(16, 32), dim3(256), 0, stream>>>(ctx, wdT, b_dense, out);
}

// Round 11
// 199.582 us; speedup vs baseline: 1.4022x; 1.0200x over previous
//
#include <hip/hip_runtime.h>

#define L2E 1.44269504088896f

typedef unsigned short u16;
typedef __attribute__((ext_vector_type(8))) short bf16x8;
typedef __attribute__((ext_vector_type(4))) float f32x4;
typedef __attribute__((ext_vector_type(16))) float f32x16;

__device__ __forceinline__ u16 f2bf(float x) {
  union { float f; unsigned u; } a; a.f = x;
  return (u16)((a.u + 0x7fffu + ((a.u >> 16) & 1u)) >> 16);
}

__device__ __forceinline__ unsigned cvtpk(float lo, float hi) {
  unsigned r;
  asm("v_cvt_pk_bf16_f32 %0, %1, %2" : "=v"(r) : "v"(lo), "v"(hi));
  return r;
}

__device__ __forceinline__ float fexp2(float x) {
  float r;
  asm("v_exp_f32 %0, %1" : "=v"(r) : "v"(x));
  return r;
}

__device__ __forceinline__ void gll16(const u16* g, u16* lds) {
  __builtin_amdgcn_global_load_lds(
      (const __attribute__((address_space(1))) unsigned int*)g,
      (__attribute__((address_space(3))) unsigned int*)lds, 16, 0, 0);
}

// ---------------- fp32 -> bf16 elementwise (x4 vectorized) ----------------
__global__ __launch_bounds__(256) void cvt_bf16(const float* __restrict__ in,
                                                u16* __restrict__ out, int n4) {
  int i = blockIdx.x * 256 + threadIdx.x;
  int stride = gridDim.x * 256;
  for (; i < n4; i += stride) {
    float4 v = reinterpret_cast<const float4*>(in)[i];
    ushort4 o;
    o.x = f2bf(v.x); o.y = f2bf(v.y); o.z = f2bf(v.z); o.w = f2bf(v.w);
    reinterpret_cast<ushort4*>(out)[i] = o;
  }
}

// ---------------- fp32 [K][N] -> bf16 [N][K] (tiled transpose) ----------------
__global__ __launch_bounds__(256) void transpose_cvt(const float* __restrict__ in,
                                                     u16* __restrict__ out,
                                                     int K, int N) {
  __shared__ float tile[32][33];
  int n0 = blockIdx.x * 32, k0 = blockIdx.y * 32;
  int tx = threadIdx.x & 31, ty = threadIdx.x >> 5;
  for (int r = ty; r < 32; r += 8)
    tile[r][tx] = in[(k0 + r) * N + n0 + tx];
  __syncthreads();
  for (int r = ty; r < 32; r += 8)
    out[(n0 + r) * K + k0 + tx] = f2bf(tile[tx][r]);
}

// ---------------- QKV GEMM: dbuf + counted vmcnt (T3/T4 2-phase) ----------------
// Vt is stored with s-index bits 2<->3 swapped (slot-order layout for attn PV).
__global__ __launch_bounds__(256) void gemm_qkv(
    const u16* __restrict__ A, const u16* __restrict__ Bt,
    const float* __restrict__ bias,
    u16* __restrict__ Qo, u16* __restrict__ Ko, u16* __restrict__ Vt) {
  __shared__ __attribute__((aligned(16))) u16 As[2][128 * 64];
  __shared__ __attribute__((aligned(16))) u16 Bs[2][128 * 64];
  const int t = threadIdx.x, w = t >> 6, l = t & 63;
  const int m0 = blockIdx.y * 128, n0 = blockIdx.x * 128;
  const int lr = l & 15, lk = l >> 4;
  const int wr = (w >> 1) * 64, wc = (w & 1) * 64;
  const int sr = l >> 3;                 // 0..7
  const int sch = (l & 7) ^ sr;          // swizzled chunk for staging source
  f32x4 acc[4][4] = {};

#define QSTAGE(bi, k0)                                                        \
  do {                                                                        \
    _Pragma("unroll")                                                         \
    for (int j = 0; j < 4; ++j) {                                             \
      const int rb = w * 32 + j * 8;                                          \
      gll16(A + (size_t)(m0 + rb + sr) * 1024 + (k0) + sch * 8,               \
            &As[bi][rb * 64]);                                                \
      gll16(Bt + (size_t)(n0 + rb + sr) * 1024 + (k0) + sch * 8,              \
            &Bs[bi][rb * 64]);                                                \
    }                                                                         \
  } while (0)

  QSTAGE(0, 0);
  for (int kt = 0; kt < 16; ++kt) {
    const int buf = kt & 1;
    if (kt < 15) {
      QSTAGE(buf ^ 1, (kt + 1) * 64);
      asm volatile("s_waitcnt vmcnt(8)" ::: "memory");  // current tile landed
    } else {
      asm volatile("s_waitcnt vmcnt(0)" ::: "memory");
    }
    __builtin_amdgcn_s_barrier();
    const u16* Asb = As[buf];
    const u16* Bsb = Bs[buf];
#pragma unroll
    for (int kk = 0; kk < 2; ++kk) {
      bf16x8 a[4], b[4];
#pragma unroll
      for (int mf = 0; mf < 4; ++mf) {
        const int row = wr + mf * 16 + lr;
        const int ch = (kk * 4 + lk) ^ (row & 7);
        a[mf] = *reinterpret_cast<const bf16x8*>(&Asb[row * 64 + ch * 8]);
      }
#pragma unroll
      for (int nf = 0; nf < 4; ++nf) {
        const int row = wc + nf * 16 + lr;
        const int ch = (kk * 4 + lk) ^ (row & 7);
        b[nf] = *reinterpret_cast<const bf16x8*>(&Bsb[row * 64 + ch * 8]);
      }
#pragma unroll
      for (int mf = 0; mf < 4; ++mf)
#pragma unroll
        for (int nf = 0; nf < 4; ++nf)
          acc[mf][nf] = __builtin_amdgcn_mfma_f32_16x16x32_bf16(a[mf], b[nf],
                                                                acc[mf][nf], 0, 0, 0);
    }
    asm volatile("" ::: "memory");
    __builtin_amdgcn_s_barrier();  // readers done before next STAGE overwrites
  }
#undef QSTAGE

  const float QSC = 0.125f * L2E;  // fold score-scale + log2(e) into Q
#pragma unroll
  for (int mf = 0; mf < 4; ++mf)
#pragma unroll
    for (int nf = 0; nf < 4; ++nf) {
      const int gc = n0 + wc + nf * 16 + lr;
      const int h = gc / 192, j = gc - h * 192;
      const int part = j >> 6, d = j & 63;
      const float bv = bias[gc];
      const int gr0 = m0 + wr + mf * 16 + lk * 4;
      const int b_ = gr0 >> 11, s0 = gr0 & 2047;
      if (part == 2) {
        // slot-order layout: swap bits 2<->3 of the s index (quad-safe:
        // bits 0..1 are the intra-quad offset)
        const int s0p = (s0 & ~0xC) | ((s0 & 4) << 1) | ((s0 & 8) >> 1);
        union { ushort4 s; unsigned u[2]; } pk;
        pk.u[0] = cvtpk(acc[mf][nf][0] + bv, acc[mf][nf][1] + bv);
        pk.u[1] = cvtpk(acc[mf][nf][2] + bv, acc[mf][nf][3] + bv);
        *reinterpret_cast<ushort4*>(
            &Vt[((size_t)(b_ * 16 + h) * 64 + d) * 2048 + s0p]) = pk.s;
      } else if (part == 0) {
#pragma unroll
        for (int r = 0; r < 4; ++r)
          Qo[((size_t)(b_ * 16 + h) * 2048 + s0 + r) * 64 + d] =
              f2bf((acc[mf][nf][r] + bv) * QSC);
      } else {
#pragma unroll
        for (int r = 0; r < 4; ++r)
          Ko[((size_t)(b_ * 16 + h) * 2048 + s0 + r) * 64 + d] =
              f2bf(acc[mf][nf][r] + bv);
      }
    }
}

// ---------------- flash attention, swapped-operand 32x32x16, zero-shuffle P ----------------
// Grid: 512 blocks (XCD-chunked swizzle), block 256 = 4 waves; wave owns 32 q-rows.
// Vt comes pre-permuted (s bits 2<->3) so the PV B-fragment packs straight from
// each lane's own QK^T output registers: crow(r,hi) ownership == MFMA slot order.
__global__ __launch_bounds__(256) void attn2(
    const u16* __restrict__ Q, const u16* __restrict__ K,
    const u16* __restrict__ Vt, u16* __restrict__ ctx) {
  __shared__ __attribute__((aligned(16))) u16 Ks[2][64 * 64];
  __shared__ __attribute__((aligned(16))) u16 Vs[2][64 * 64];
  const int t = threadIdx.x;
  const int w = t >> 6, l = t & 63;
  const int lq = l & 31, hi = l >> 5;
  const int bid = blockIdx.x;
  const int wg = (bid & 7) * 64 + (bid >> 3);
  const int bh = wg >> 4, qt = wg & 15;
  const int b = bh >> 4, h = bh & 15;
  const u16* Qp = Q + (size_t)bh * (2048 * 64);
  const u16* Kp = K + (size_t)bh * (2048 * 64);
  const u16* Vp = Vt + (size_t)bh * (64 * 2048);
  const int q0w = qt * 128 + w * 32;

  const int srow = w * 16 + (l >> 3);
  const int sch = (l & 7) ^ ((l >> 3) & 7);

  bf16x8 qf[4];
#pragma unroll
  for (int i = 0; i < 4; ++i)
    qf[i] = *reinterpret_cast<const bf16x8*>(
        &Qp[(size_t)(q0w + lq) * 64 + i * 16 + hi * 8]);

  bf16x8 ones;
#pragma unroll
  for (int j = 0; j < 8; ++j) ones[j] = (short)0x3F80;  // bf16 1.0

  f32x16 o0 = {}, o1 = {}, osum = {};
  float mrun = -1e30f;

#define STG(bufi, kk0)                                                         \
  do {                                                                         \
    gll16(Kp + (size_t)((kk0) + srow) * 64 + sch * 8,                          \
          &Ks[bufi][(w * 16) * 64]);                                           \
    gll16(Kp + (size_t)((kk0) + srow + 8) * 64 + sch * 8,                      \
          &Ks[bufi][(w * 16 + 8) * 64]);                                       \
    gll16(Vp + (size_t)srow * 2048 + (kk0) + sch * 8,                          \
          &Vs[bufi][(w * 16) * 64]);                                           \
    gll16(Vp + (size_t)(srow + 8) * 2048 + (kk0) + sch * 8,                    \
          &Vs[bufi][(w * 16 + 8) * 64]);                                       \
  } while (0)

  // P fragment: direct pack — lane's own p[8kb..8kb+7] are exactly its
  // B-operand slots (hi*8..hi*8+7) for the kb-th 16-krow MFMA step, because
  // V rows are stored in slot order (bits 2<->3 swapped at gemm_qkv).
#define PVSTEP(pp, sub)                                                        \
  do {                                                                         \
    _Pragma("unroll")                                                          \
    for (int kb = 0; kb < 2; ++kb) {                                           \
      union { unsigned u[4]; bf16x8 v; } pu;                                   \
      pu.u[0] = cvtpk(pp[8 * kb + 0], pp[8 * kb + 1]);                         \
      pu.u[1] = cvtpk(pp[8 * kb + 2], pp[8 * kb + 3]);                         \
      pu.u[2] = cvtpk(pp[8 * kb + 4], pp[8 * kb + 5]);                         \
      pu.u[3] = cvtpk(pp[8 * kb + 6], pp[8 * kb + 7]);                         \
      const int ch = (((sub) * 4 + kb * 2 + hi) ^ (lq & 7)) * 8;               \
      bf16x8 v0 = *reinterpret_cast<const bf16x8*>(&VB[lq * 64 + ch]);         \
      o0 = __builtin_amdgcn_mfma_f32_32x32x16_bf16(v0, pu.v, o0, 0, 0, 0);     \
      bf16x8 v1 = *reinterpret_cast<const bf16x8*>(&VB[(32 + lq) * 64 + ch]);  \
      o1 = __builtin_amdgcn_mfma_f32_32x32x16_bf16(v1, pu.v, o1, 0, 0, 0);     \
      osum = __builtin_amdgcn_mfma_f32_32x32x16_bf16(ones, pu.v, osum, 0, 0, 0);\
    }                                                                          \
  } while (0)

  STG(0, 0);

#pragma unroll 2
  for (int kt = 0; kt < 32; ++kt) {
    const int buf = kt & 1;
    if (kt < 31) {
      STG(buf ^ 1, (kt + 1) * 64);
      asm volatile("s_waitcnt vmcnt(4)" ::: "memory");  // current tile landed
    } else {
      asm volatile("s_waitcnt vmcnt(0)" ::: "memory");
    }
    __builtin_amdgcn_s_barrier();
    const u16* KB = Ks[buf];
    const u16* VB = Vs[buf];

    // S^T = K Q^T : lane holds col q = lq, rows k = crow(reg,hi)(+32 for s1)
    f32x16 s0 = {}, s1 = {};
#pragma unroll
    for (int i = 0; i < 4; ++i) {
      const int sl = ((2 * i + hi) ^ (lq & 7)) * 8;
      bf16x8 k0f = *reinterpret_cast<const bf16x8*>(&KB[lq * 64 + sl]);
      s0 = __builtin_amdgcn_mfma_f32_32x32x16_bf16(k0f, qf[i], s0, 0, 0, 0);
      bf16x8 k1f = *reinterpret_cast<const bf16x8*>(&KB[(32 + lq) * 64 + sl]);
      s1 = __builtin_amdgcn_mfma_f32_32x32x16_bf16(k1f, qf[i], s1, 0, 0, 0);
    }

    // in-lane max over 32 values + partner-lane exchange (lane ^ 32)
    float mx[8];
#pragma unroll
    for (int r = 0; r < 8; ++r)
      mx[r] = fmaxf(fmaxf(s0[r], s0[r + 8]), fmaxf(s1[r], s1[r + 8]));
#pragma unroll
    for (int r = 0; r < 4; ++r) mx[r] = fmaxf(mx[r], mx[r + 4]);
    float tm = fmaxf(fmaxf(mx[0], mx[1]), fmaxf(mx[2], mx[3]));
    tm = fmaxf(tm, __shfl_xor(tm, 32));

    // deferred-max rescale (THR=8 in exp2 domain)
    if (!__all(tm - mrun <= 8.0f)) {
      float mnew = fmaxf(mrun, tm);
      float al = fexp2(mrun - mnew);
      mrun = mnew;
#pragma unroll
      for (int r = 0; r < 16; ++r) { o0[r] *= al; o1[r] *= al; }
      osum[0] *= al;
    }

    float p0[16], p1[16];
#pragma unroll
    for (int r = 0; r < 16; ++r) p0[r] = fexp2(s0[r] - mrun);
#pragma unroll
    for (int r = 0; r < 16; ++r) p1[r] = fexp2(s1[r] - mrun);

    PVSTEP(p0, 0);
    PVSTEP(p1, 1);

    asm volatile("" ::: "memory");
    __builtin_amdgcn_s_barrier();  // readers done before next STG overwrites
  }
#undef STG
#undef PVSTEP

  // epilogue: normalize, pack quads (4 consecutive d), store ctx[b][s=q][h*64+d]
  const float inv = 1.0f / osum[0];
  u16* cp = ctx + ((size_t)(b * 2048 + q0w + lq) * 1024 + h * 64);
#pragma unroll
  for (int a = 0; a < 4; ++a) {
    const int d = 8 * a + 4 * hi;
    union { ushort4 s; unsigned u[2]; } pk;
    pk.u[0] = cvtpk(o0[4 * a + 0] * inv, o0[4 * a + 1] * inv);
    pk.u[1] = cvtpk(o0[4 * a + 2] * inv, o0[4 * a + 3] * inv);
    *reinterpret_cast<ushort4*>(cp + d) = pk.s;
    pk.u[0] = cvtpk(o1[4 * a + 0] * inv, o1[4 * a + 1] * inv);
    pk.u[1] = cvtpk(o1[4 * a + 2] * inv, o1[4 * a + 3] * inv);
    *reinterpret_cast<ushort4*>(cp + 32 + d) = pk.s;
  }
}

// ---------------- dense GEMM: 128x64 tiles, dbuf + counted vmcnt -> fp32 ----------------
__global__ __launch_bounds__(256) void gemm_dense(
    const u16* __restrict__ A, const u16* __restrict__ Bt,
    const float* __restrict__ bias, float* __restrict__ out) {
  __shared__ __attribute__((aligned(16))) u16 As[2][128 * 64];
  __shared__ __attribute__((aligned(16))) u16 Bs[2][64 * 64];
  const int t = threadIdx.x, w = t >> 6, l = t & 63;
  const int m0 = blockIdx.y * 128, n0 = blockIdx.x * 64;
  const int lr = l & 15, lk = l >> 4;
  const int wr = (w >> 1) * 64, wc = (w & 1) * 32;
  const int sr = l >> 3;
  const int sch = (l & 7) ^ sr;
  f32x4 acc[4][2] = {};

#define DSTAGE(bi, k0)                                                        \
  do {                                                                        \
    _Pragma("unroll")                                                         \
    for (int j = 0; j < 4; ++j) {                                             \
      const int rb = w * 32 + j * 8;                                          \
      gll16(A + (size_t)(m0 + rb + sr) * 1024 + (k0) + sch * 8,               \
            &As[bi][rb * 64]);                                                \
    }                                                                         \
    _Pragma("unroll")                                                         \
    for (int j = 0; j < 2; ++j) {                                             \
      const int rb = w * 16 + j * 8;                                          \
      gll16(Bt + (size_t)(n0 + rb + sr) * 1024 + (k0) + sch * 8,              \
            &Bs[bi][rb * 64]);                                                \
    }                                                                         \
  } while (0)

  DSTAGE(0, 0);
  for (int kt = 0; kt < 16; ++kt) {
    const int buf = kt & 1;
    if (kt < 15) {
      DSTAGE(buf ^ 1, (kt + 1) * 64);
      asm volatile("s_waitcnt vmcnt(6)" ::: "memory");
    } else {
      asm volatile("s_waitcnt vmcnt(0)" ::: "memory");
    }
    __builtin_amdgcn_s_barrier();
    const u16* Asb = As[buf];
    const u16* Bsb = Bs[buf];
#pragma unroll
    for (int kk = 0; kk < 2; ++kk) {
      bf16x8 a[4], b[2];
#pragma unroll
      for (int mf = 0; mf < 4; ++mf) {
        const int row = wr + mf * 16 + lr;
        const int ch = (kk * 4 + lk) ^ (row & 7);
        a[mf] = *reinterpret_cast<const bf16x8*>(&Asb[row * 64 + ch * 8]);
      }
#pragma unroll
      for (int nf = 0; nf < 2; ++nf) {
        const int row = wc + nf * 16 + lr;
        const int ch = (kk * 4 + lk) ^ (row & 7);
        b[nf] = *reinterpret_cast<const bf16x8*>(&Bsb[row * 64 + ch * 8]);
      }
#pragma unroll
      for (int mf = 0; mf < 4; ++mf)
#pragma unroll
        for (int nf = 0; nf < 2; ++nf)
          acc[mf][nf] = __builtin_amdgcn_mfma_f32_16x16x32_bf16(a[mf], b[nf],
                                                                acc[mf][nf], 0, 0, 0);
    }
    asm volatile("" ::: "memory");
    __builtin_amdgcn_s_barrier();
  }
#undef DSTAGE

#pragma unroll
  for (int mf = 0; mf < 4; ++mf)
#pragma unroll
    for (int nf = 0; nf < 2; ++nf)
#pragma unroll
      for (int r = 0; r < 4; ++r) {
        int gr = m0 + wr + mf * 16 + lk * 4 + r;
        int gc = n0 + wc + nf * 16 + lr;
        out[(size_t)gr * 1024 + gc] = acc[mf][nf][r] + bias[gc];
      }
}

extern "C" void kernel_launch(void* const* d_in, const int* in_sizes, int n_in,
                              void* d_out, int out_size, void* d_ws, size_t ws_size,
                              hipStream_t stream) {
  const float* hs = (const float*)d_in[0];       // [2,2048,1024]
  const float* w_qkv = (const float*)d_in[1];    // [1024,3072]
  const float* b_qkv = (const float*)d_in[2];    // [3072]
  const float* w_dense = (const float*)d_in[3];  // [1024,1024]
  const float* b_dense = (const float*)d_in[4];  // [1024]
  float* out = (float*)d_out;

  char* ws = (char*)d_ws;
  u16* hsb = (u16*)(ws);                  // 8 MB  [4096][1024]
  u16* wqkvT = (u16*)(ws + (8ll << 20));  // 6 MB  [3072][1024]
  u16* wdT = (u16*)(ws + (14ll << 20));   // 2 MB  [1024][1024]
  u16* Qb = (u16*)(ws + (16ll << 20));    // 8 MB  [2][16][2048][64] (pre-scaled)
  u16* Kb = (u16*)(ws + (24ll << 20));    // 8 MB
  u16* Vtb = (u16*)(ws + (32ll << 20));   // 8 MB  [2][16][64][2048] (slot-order s)
  u16* ctx = (u16*)(ws + (40ll << 20));   // 8 MB  [4096][1024]

  cvt_bf16<<<dim3(2048), dim3(256), 0, stream>>>(hs, hsb, (4096 * 1024) / 4);
  transpose_cvt<<<dim3(96, 32), dim3(256), 0, stream>>>(w_qkv, wqkvT, 1024, 3072);
  transpose_cvt<<<dim3(32, 32), dim3(256), 0, stream>>>(w_dense, wdT, 1024, 1024);
  gemm_qkv<<<dim3(24, 32), dim3(256), 0, stream>>>(hsb, wqkvT, b_qkv, Qb, Kb, Vtb);
  attn2<<<dim3(512), dim3(256), 0, stream>>>(Qb, Kb, Vtb, ctx);
  gemm_dense<<<dim3(16, 32), dim3(256), 0, stream>>>(ctx, wdT, b_dense, out);
}

// Round 13
// 191.773 us; speedup vs baseline: 1.4593x; 1.0407x over previous
//
#include <hip/hip_runtime.h>

#define L2E 1.44269504088896f

typedef unsigned short u16;
typedef __attribute__((ext_vector_type(8))) short bf16x8;
typedef __attribute__((ext_vector_type(4))) float f32x4;
typedef __attribute__((ext_vector_type(16))) float f32x16;

__device__ __forceinline__ u16 f2bf(float x) {
  union { float f; unsigned u; } a; a.f = x;
  return (u16)((a.u + 0x7fffu + ((a.u >> 16) & 1u)) >> 16);
}

__device__ __forceinline__ unsigned cvtpk(float lo, float hi) {
  unsigned r;
  asm("v_cvt_pk_bf16_f32 %0, %1, %2" : "=v"(r) : "v"(lo), "v"(hi));
  return r;
}

__device__ __forceinline__ float fexp2(float x) {
  float r;
  asm("v_exp_f32 %0, %1" : "=v"(r) : "v"(x));
  return r;
}

__device__ __forceinline__ void gll16(const u16* g, u16* lds) {
  __builtin_amdgcn_global_load_lds(
      (const __attribute__((address_space(1))) unsigned int*)g,
      (__attribute__((address_space(3))) unsigned int*)lds, 16, 0, 0);
}

// ---------------- fused prep: cvt hs->bf16 + both weight transposes ----------------
// grid = 1024 (cvt) + 3072 (w_qkv T) + 1024 (w_dense T) = 5120 blocks
__global__ __launch_bounds__(256) void prep(
    const float* __restrict__ hs, u16* __restrict__ hsb,
    const float* __restrict__ wq, u16* __restrict__ wqT,
    const float* __restrict__ wd, u16* __restrict__ wdT) {
  __shared__ float tile[32][33];
  const int bid = blockIdx.x;
  if (bid < 1024) {
    int i = bid * 256 + threadIdx.x;
    for (; i < (4096 * 1024 / 4); i += 1024 * 256) {
      float4 v = reinterpret_cast<const float4*>(hs)[i];
      ushort4 o;
      o.x = f2bf(v.x); o.y = f2bf(v.y); o.z = f2bf(v.z); o.w = f2bf(v.w);
      reinterpret_cast<ushort4*>(hsb)[i] = o;
    }
    return;
  }
  const float* in; u16* out; int K, N, n0, k0;
  if (bid < 1024 + 3072) {
    const int idx = bid - 1024;
    in = wq; out = wqT; K = 1024; N = 3072;
    n0 = (idx % 96) * 32; k0 = (idx / 96) * 32;
  } else {
    const int idx = bid - 4096;
    in = wd; out = wdT; K = 1024; N = 1024;
    n0 = (idx & 31) * 32; k0 = (idx >> 5) * 32;
  }
  const int tx = threadIdx.x & 31, ty = threadIdx.x >> 5;
  for (int r = ty; r < 32; r += 8)
    tile[r][tx] = in[(k0 + r) * N + n0 + tx];
  __syncthreads();
  for (int r = ty; r < 32; r += 8)
    out[(n0 + r) * K + k0 + tx] = f2bf(tile[tx][r]);
}

// ---------------- QKV GEMM: dbuf + counted vmcnt (T3/T4 2-phase) ----------------
// Vt is stored with s-index bits 2<->3 swapped (slot-order layout for attn PV).
__global__ __launch_bounds__(256) void gemm_qkv(
    const u16* __restrict__ A, const u16* __restrict__ Bt,
    const float* __restrict__ bias,
    u16* __restrict__ Qo, u16* __restrict__ Ko, u16* __restrict__ Vt) {
  __shared__ __attribute__((aligned(16))) u16 As[2][128 * 64];
  __shared__ __attribute__((aligned(16))) u16 Bs[2][128 * 64];
  const int t = threadIdx.x, w = t >> 6, l = t & 63;
  const int m0 = blockIdx.y * 128, n0 = blockIdx.x * 128;
  const int lr = l & 15, lk = l >> 4;
  const int wr = (w >> 1) * 64, wc = (w & 1) * 64;
  const int sr = l >> 3;                 // 0..7
  const int sch = (l & 7) ^ sr;          // swizzled chunk for staging source
  f32x4 acc[4][4] = {};

#define QSTAGE(bi, k0)                                                        \
  do {                                                                        \
    _Pragma("unroll")                                                         \
    for (int j = 0; j < 4; ++j) {                                             \
      const int rb = w * 32 + j * 8;                                          \
      gll16(A + (size_t)(m0 + rb + sr) * 1024 + (k0) + sch * 8,               \
            &As[bi][rb * 64]);                                                \
      gll16(Bt + (size_t)(n0 + rb + sr) * 1024 + (k0) + sch * 8,              \
            &Bs[bi][rb * 64]);                                                \
    }                                                                         \
  } while (0)

  QSTAGE(0, 0);
  for (int kt = 0; kt < 16; ++kt) {
    const int buf = kt & 1;
    if (kt < 15) {
      QSTAGE(buf ^ 1, (kt + 1) * 64);
      asm volatile("s_waitcnt vmcnt(8)" ::: "memory");  // current tile landed
    } else {
      asm volatile("s_waitcnt vmcnt(0)" ::: "memory");
    }
    __builtin_amdgcn_s_barrier();
    const u16* Asb = As[buf];
    const u16* Bsb = Bs[buf];
#pragma unroll
    for (int kk = 0; kk < 2; ++kk) {
      bf16x8 a[4], b[4];
#pragma unroll
      for (int mf = 0; mf < 4; ++mf) {
        const int row = wr + mf * 16 + lr;
        const int ch = (kk * 4 + lk) ^ (row & 7);
        a[mf] = *reinterpret_cast<const bf16x8*>(&Asb[row * 64 + ch * 8]);
      }
#pragma unroll
      for (int nf = 0; nf < 4; ++nf) {
        const int row = wc + nf * 16 + lr;
        const int ch = (kk * 4 + lk) ^ (row & 7);
        b[nf] = *reinterpret_cast<const bf16x8*>(&Bsb[row * 64 + ch * 8]);
      }
#pragma unroll
      for (int mf = 0; mf < 4; ++mf)
#pragma unroll
        for (int nf = 0; nf < 4; ++nf)
          acc[mf][nf] = __builtin_amdgcn_mfma_f32_16x16x32_bf16(a[mf], b[nf],
                                                                acc[mf][nf], 0, 0, 0);
    }
    asm volatile("" ::: "memory");
    __builtin_amdgcn_s_barrier();  // readers done before next STAGE overwrites
  }
#undef QSTAGE

  const float QSC = 0.125f * L2E;  // fold score-scale + log2(e) into Q
#pragma unroll
  for (int mf = 0; mf < 4; ++mf)
#pragma unroll
    for (int nf = 0; nf < 4; ++nf) {
      const int gc = n0 + wc + nf * 16 + lr;
      const int h = gc / 192, j = gc - h * 192;
      const int part = j >> 6, d = j & 63;
      const float bv = bias[gc];
      const int gr0 = m0 + wr + mf * 16 + lk * 4;
      const int b_ = gr0 >> 11, s0 = gr0 & 2047;
      if (part == 2) {
        // slot-order layout: swap bits 2<->3 of the s index (quad-safe:
        // bits 0..1 are the intra-quad offset)
        const int s0p = (s0 & ~0xC) | ((s0 & 4) << 1) | ((s0 & 8) >> 1);
        union { ushort4 s; unsigned u[2]; } pk;
        pk.u[0] = cvtpk(acc[mf][nf][0] + bv, acc[mf][nf][1] + bv);
        pk.u[1] = cvtpk(acc[mf][nf][2] + bv, acc[mf][nf][3] + bv);
        *reinterpret_cast<ushort4*>(
            &Vt[((size_t)(b_ * 16 + h) * 64 + d) * 2048 + s0p]) = pk.s;
      } else if (part == 0) {
#pragma unroll
        for (int r = 0; r < 4; ++r)
          Qo[((size_t)(b_ * 16 + h) * 2048 + s0 + r) * 64 + d] =
              f2bf((acc[mf][nf][r] + bv) * QSC);
      } else {
#pragma unroll
        for (int r = 0; r < 4; ++r)
          Ko[((size_t)(b_ * 16 + h) * 2048 + s0 + r) * 64 + d] =
              f2bf(acc[mf][nf][r] + bv);
      }
    }
}

// ---------------- flash attention: KVBLK=128 (2 sub-tiles per barrier pair) ----------------
// Grid: 512 blocks (XCD-chunked swizzle), block 256 = 4 waves; wave owns 32 q-rows.
// Zero-shuffle P: Vt pre-permuted (s bits 2<->3) so PV B-frag packs from own regs.
__global__ __launch_bounds__(256) void attn2(
    const u16* __restrict__ Q, const u16* __restrict__ K,
    const u16* __restrict__ Vt, u16* __restrict__ ctx) {
  __shared__ __attribute__((aligned(16))) u16 Ks[2][2][64 * 64];
  __shared__ __attribute__((aligned(16))) u16 Vs[2][2][64 * 64];
  const int t = threadIdx.x;
  const int w = t >> 6, l = t & 63;
  const int lq = l & 31, hi = l >> 5;
  const int bid = blockIdx.x;
  const int wg = (bid & 7) * 64 + (bid >> 3);
  const int bh = wg >> 4, qt = wg & 15;
  const int b = bh >> 4, h = bh & 15;
  const u16* Qp = Q + (size_t)bh * (2048 * 64);
  const u16* Kp = K + (size_t)bh * (2048 * 64);
  const u16* Vp = Vt + (size_t)bh * (64 * 2048);
  const int q0w = qt * 128 + w * 32;

  const int srow = w * 16 + (l >> 3);
  const int sch = (l & 7) ^ ((l >> 3) & 7);

  bf16x8 qf[4];
#pragma unroll
  for (int i = 0; i < 4; ++i)
    qf[i] = *reinterpret_cast<const bf16x8*>(
        &Qp[(size_t)(q0w + lq) * 64 + i * 16 + hi * 8]);

  bf16x8 ones;
#pragma unroll
  for (int j = 0; j < 8; ++j) ones[j] = (short)0x3F80;  // bf16 1.0

  f32x16 o0 = {}, o1 = {}, osum = {};
  float mrun = -1e30f;

  // stage one 64-row sub-tile (K rows srow/srow+8, V d-rows srow/srow+8)
#define STG1(bufi, sub, kk0)                                                   \
  do {                                                                         \
    gll16(Kp + (size_t)((kk0) + srow) * 64 + sch * 8,                          \
          &Ks[bufi][sub][(w * 16) * 64]);                                      \
    gll16(Kp + (size_t)((kk0) + srow + 8) * 64 + sch * 8,                      \
          &Ks[bufi][sub][(w * 16 + 8) * 64]);                                  \
    gll16(Vp + (size_t)srow * 2048 + (kk0) + sch * 8,                          \
          &Vs[bufi][sub][(w * 16) * 64]);                                      \
    gll16(Vp + (size_t)(srow + 8) * 2048 + (kk0) + sch * 8,                    \
          &Vs[bufi][sub][(w * 16 + 8) * 64]);                                  \
  } while (0)

#define STGPAIR(bufi, kk0)                                                     \
  do { STG1(bufi, 0, kk0); STG1(bufi, 1, (kk0) + 64); } while (0)

  // P fragment: direct pack — lane's own p[8kb..8kb+7] are its B-operand
  // slots because V rows are stored in slot order (bits 2<->3 swapped).
#define PVSTEP(pp, sub)                                                        \
  do {                                                                         \
    _Pragma("unroll")                                                          \
    for (int kb = 0; kb < 2; ++kb) {                                           \
      union { unsigned u[4]; bf16x8 v; } pu;                                   \
      pu.u[0] = cvtpk(pp[8 * kb + 0], pp[8 * kb + 1]);                         \
      pu.u[1] = cvtpk(pp[8 * kb + 2], pp[8 * kb + 3]);                         \
      pu.u[2] = cvtpk(pp[8 * kb + 4], pp[8 * kb + 5]);                         \
      pu.u[3] = cvtpk(pp[8 * kb + 6], pp[8 * kb + 7]);                         \
      const int ch = (((sub) * 4 + kb * 2 + hi) ^ (lq & 7)) * 8;               \
      bf16x8 v0 = *reinterpret_cast<const bf16x8*>(&VB[lq * 64 + ch]);         \
      o0 = __builtin_amdgcn_mfma_f32_32x32x16_bf16(v0, pu.v, o0, 0, 0, 0);     \
      bf16x8 v1 = *reinterpret_cast<const bf16x8*>(&VB[(32 + lq) * 64 + ch]);  \
      o1 = __builtin_amdgcn_mfma_f32_32x32x16_bf16(v1, pu.v, o1, 0, 0, 0);     \
      osum = __builtin_amdgcn_mfma_f32_32x32x16_bf16(ones, pu.v, osum, 0, 0, 0);\
    }                                                                          \
  } while (0)

  STGPAIR(0, 0);

  for (int kt2 = 0; kt2 < 16; ++kt2) {
    const int buf = kt2 & 1;
    if (kt2 < 15) {
      STGPAIR(buf ^ 1, (kt2 + 1) * 128);
      asm volatile("s_waitcnt vmcnt(8)" ::: "memory");  // current pair landed
    } else {
      asm volatile("s_waitcnt vmcnt(0)" ::: "memory");
    }
    __builtin_amdgcn_s_barrier();

#pragma unroll
    for (int sub = 0; sub < 2; ++sub) {
      const u16* KB = Ks[buf][sub];
      const u16* VB = Vs[buf][sub];

      // S^T = K Q^T : lane holds col q = lq, rows k = crow(reg,hi)(+32 for s1)
      f32x16 s0 = {}, s1 = {};
#pragma unroll
      for (int i = 0; i < 4; ++i) {
        const int sl = ((2 * i + hi) ^ (lq & 7)) * 8;
        bf16x8 k0f = *reinterpret_cast<const bf16x8*>(&KB[lq * 64 + sl]);
        s0 = __builtin_amdgcn_mfma_f32_32x32x16_bf16(k0f, qf[i], s0, 0, 0, 0);
        bf16x8 k1f = *reinterpret_cast<const bf16x8*>(&KB[(32 + lq) * 64 + sl]);
        s1 = __builtin_amdgcn_mfma_f32_32x32x16_bf16(k1f, qf[i], s1, 0, 0, 0);
      }

      // in-lane max over 32 values + partner-lane exchange (lane ^ 32)
      float mx[8];
#pragma unroll
      for (int r = 0; r < 8; ++r)
        mx[r] = fmaxf(fmaxf(s0[r], s0[r + 8]), fmaxf(s1[r], s1[r + 8]));
#pragma unroll
      for (int r = 0; r < 4; ++r) mx[r] = fmaxf(mx[r], mx[r + 4]);
      float tm = fmaxf(fmaxf(mx[0], mx[1]), fmaxf(mx[2], mx[3]));
      tm = fmaxf(tm, __shfl_xor(tm, 32));

      // deferred-max rescale (THR=8 in exp2 domain)
      if (!__all(tm - mrun <= 8.0f)) {
        float mnew = fmaxf(mrun, tm);
        float al = fexp2(mrun - mnew);
        mrun = mnew;
#pragma unroll
        for (int r = 0; r < 16; ++r) { o0[r] *= al; o1[r] *= al; }
        osum[0] *= al;
      }

      float p0[16], p1[16];
#pragma unroll
      for (int r = 0; r < 16; ++r) p0[r] = fexp2(s0[r] - mrun);
#pragma unroll
      for (int r = 0; r < 16; ++r) p1[r] = fexp2(s1[r] - mrun);

      PVSTEP(p0, 0);
      PVSTEP(p1, 1);
    }

    asm volatile("" ::: "memory");
    __builtin_amdgcn_s_barrier();  // readers done before next STGPAIR overwrites
  }
#undef STG1
#undef STGPAIR
#undef PVSTEP

  // epilogue: normalize, pack quads (4 consecutive d), store ctx[b][s=q][h*64+d]
  const float inv = 1.0f / osum[0];
  u16* cp = ctx + ((size_t)(b * 2048 + q0w + lq) * 1024 + h * 64);
#pragma unroll
  for (int a = 0; a < 4; ++a) {
    const int d = 8 * a + 4 * hi;
    union { ushort4 s; unsigned u[2]; } pk;
    pk.u[0] = cvtpk(o0[4 * a + 0] * inv, o0[4 * a + 1] * inv);
    pk.u[1] = cvtpk(o0[4 * a + 2] * inv, o0[4 * a + 3] * inv);
    *reinterpret_cast<ushort4*>(cp + d) = pk.s;
    pk.u[0] = cvtpk(o1[4 * a + 0] * inv, o1[4 * a + 1] * inv);
    pk.u[1] = cvtpk(o1[4 * a + 2] * inv, o1[4 * a + 3] * inv);
    *reinterpret_cast<ushort4*>(cp + 32 + d) = pk.s;
  }
}

// ---------------- dense GEMM: 128x64 tiles, dbuf + counted vmcnt -> fp32 ----------------
__global__ __launch_bounds__(256) void gemm_dense(
    const u16* __restrict__ A, const u16* __restrict__ Bt,
    const float* __restrict__ bias, float* __restrict__ out) {
  __shared__ __attribute__((aligned(16))) u16 As[2][128 * 64];
  __shared__ __attribute__((aligned(16))) u16 Bs[2][64 * 64];
  const int t = threadIdx.x, w = t >> 6, l = t & 63;
  const int m0 = blockIdx.y * 128, n0 = blockIdx.x * 64;
  const int lr = l & 15, lk = l >> 4;
  const int wr = (w >> 1) * 64, wc = (w & 1) * 32;
  const int sr = l >> 3;
  const int sch = (l & 7) ^ sr;
  f32x4 acc[4][2] = {};

#define DSTAGE(bi, k0)                                                        \
  do {                                                                        \
    _Pragma("unroll")                                                         \
    for (int j = 0; j < 4; ++j) {                                             \
      const int rb = w * 32 + j * 8;                                          \
      gll16(A + (size_t)(m0 + rb + sr) * 1024 + (k0) + sch * 8,               \
            &As[bi][rb * 64]);                                                \
    }                                                                         \
    _Pragma("unroll")                                                         \
    for (int j = 0; j < 2; ++j) {                                             \
      const int rb = w * 16 + j * 8;                                          \
      gll16(Bt + (size_t)(n0 + rb + sr) * 1024 + (k0) + sch * 8,              \
            &Bs[bi][rb * 64]);                                                \
    }                                                                         \
  } while (0)

  DSTAGE(0, 0);
  for (int kt = 0; kt < 16; ++kt) {
    const int buf = kt & 1;
    if (kt < 15) {
      DSTAGE(buf ^ 1, (kt + 1) * 64);
      asm volatile("s_waitcnt vmcnt(6)" ::: "memory");
    } else {
      asm volatile("s_waitcnt vmcnt(0)" ::: "memory");
    }
    __builtin_amdgcn_s_barrier();
    const u16* Asb = As[buf];
    const u16* Bsb = Bs[buf];
#pragma unroll
    for (int kk = 0; kk < 2; ++kk) {
      bf16x8 a[4], b[2];
#pragma unroll
      for (int mf = 0; mf < 4; ++mf) {
        const int row = wr + mf * 16 + lr;
        const int ch = (kk * 4 + lk) ^ (row & 7);
        a[mf] = *reinterpret_cast<const bf16x8*>(&Asb[row * 64 + ch * 8]);
      }
#pragma unroll
      for (int nf = 0; nf < 2; ++nf) {
        const int row = wc + nf * 16 + lr;
        const int ch = (kk * 4 + lk) ^ (row & 7);
        b[nf] = *reinterpret_cast<const bf16x8*>(&Bsb[row * 64 + ch * 8]);
      }
#pragma unroll
      for (int mf = 0; mf < 4; ++mf)
#pragma unroll
        for (int nf = 0; nf < 2; ++nf)
          acc[mf][nf] = __builtin_amdgcn_mfma_f32_16x16x32_bf16(a[mf], b[nf],
                                                                acc[mf][nf], 0, 0, 0);
    }
    asm volatile("" ::: "memory");
    __builtin_amdgcn_s_barrier();
  }
#undef DSTAGE

#pragma unroll
  for (int mf = 0; mf < 4; ++mf)
#pragma unroll
    for (int nf = 0; nf < 2; ++nf)
#pragma unroll
      for (int r = 0; r < 4; ++r) {
        int gr = m0 + wr + mf * 16 + lk * 4 + r;
        int gc = n0 + wc + nf * 16 + lr;
        out[(size_t)gr * 1024 + gc] = acc[mf][nf][r] + bias[gc];
      }
}

extern "C" void kernel_launch(void* const* d_in, const int* in_sizes, int n_in,
                              void* d_out, int out_size, void* d_ws, size_t ws_size,
                              hipStream_t stream) {
  const float* hs = (const float*)d_in[0];       // [2,2048,1024]
  const float* w_qkv = (const float*)d_in[1];    // [1024,3072]
  const float* b_qkv = (const float*)d_in[2];    // [3072]
  const float* w_dense = (const float*)d_in[3];  // [1024,1024]
  const float* b_dense = (const float*)d_in[4];  // [1024]
  float* out = (float*)d_out;

  char* ws = (char*)d_ws;
  u16* hsb = (u16*)(ws);                  // 8 MB  [4096][1024]
  u16* wqkvT = (u16*)(ws + (8ll << 20));  // 6 MB  [3072][1024]
  u16* wdT = (u16*)(ws + (14ll << 20));   // 2 MB  [1024][1024]
  u16* Qb = (u16*)(ws + (16ll << 20));    // 8 MB  [2][16][2048][64] (pre-scaled)
  u16* Kb = (u16*)(ws + (24ll << 20));    // 8 MB
  u16* Vtb = (u16*)(ws + (32ll << 20));   // 8 MB  [2][16][64][2048] (slot-order s)
  u16* ctx = (u16*)(ws + (40ll << 20));   // 8 MB  [4096][1024]

  prep<<<dim3(5120), dim3(256), 0, stream>>>(hs, hsb, w_qkv, wqkvT, w_dense, wdT);
  gemm_qkv<<<dim3(24, 32), dim3(256), 0, stream>>>(hsb, wqkvT, b_qkv, Qb, Kb, Vtb);
  attn2<<<dim3(512), dim3(256), 0, stream>>>(Qb, Kb, Vtb, ctx);
  gemm_dense<<<dim3(16, 32), dim3(256), 0, stream>>>(ctx, wdT, b_dense, out);
}